// Round 8
// baseline (354.674 us; speedup 1.0000x reference)
//
#include <hip/hip_runtime.h>
#include <hip/hip_fp16.h>

#define N_NODES 100000
#define N_EDGES 3200000
#define N_FEAT  128
#define DIM     48
#define N_CLASS 18
#define BN_EPS  1e-5f

#define PADK 132   // W^T tile row stride (dwords)
#define PADH 68    // half-K x-tile row stride (dwords); quartet step 17%8=1 -> conflict-free row reads
#define PADD 52    // 48-wide tile row stride

#define BSH    7                                   // bucket = dst >> 7 (128 nodes)
#define BROWS  128                                 // nodes per bucket
#define NBUCK  ((N_NODES + BROWS - 1) / BROWS)     // 782
#define EPB    4096                                // edges per binning block
#define NBLK_E ((N_EDGES + EPB - 1) / EPB)         // 782

// packed edge: (src << 7) | (dst & 127).  src < 2^17, fits 24 bits.

// ---------------- bucket-granular edge preprocessing ----------------

__global__ __launch_bounds__(256) void k_bhist(const int* __restrict__ ei,
                                               int* __restrict__ bcnt) {
    __shared__ int h[NBUCK];
    const int t = threadIdx.x;
    for (int i = t; i < NBUCK; i += 256) h[i] = 0;
    __syncthreads();
    int bs = blockIdx.x * EPB;
    int ce = min(EPB, N_EDGES - bs);
    for (int i = t; i < ce; i += 256) {
        int d = ei[N_EDGES + bs + i];
        atomicAdd(&h[d >> BSH], 1);
    }
    __syncthreads();
    for (int i = t; i < NBUCK; i += 256)
        if (h[i]) atomicAdd(&bcnt[i], h[i]);
}

__global__ __launch_bounds__(1024) void k_bscan(const int* __restrict__ bcnt,
                                                int* __restrict__ bptr,
                                                int* __restrict__ bcursor) {
    __shared__ int s[1024];
    const int t = threadIdx.x;
    int v = (t < NBUCK) ? bcnt[t] : 0;
    s[t] = v;
    __syncthreads();
    for (int off = 1; off < 1024; off <<= 1) {
        int u = (t >= off) ? s[t - off] : 0;
        __syncthreads();
        s[t] += u;
        __syncthreads();
    }
    if (t < NBUCK) {
        int excl = s[t] - v;
        bptr[t] = excl;
        bcursor[t] = excl;
        if (t == NBUCK - 1) bptr[NBUCK] = s[t];
    }
}

// LDS-staged binning: packed pairs written in bucket-contiguous runs,
// one global reserve atomic per (block,bucket).
__global__ __launch_bounds__(256) void k_bin(const int* __restrict__ ei,
                                             int* __restrict__ bcursor,
                                             unsigned int* __restrict__ pairs) {
    __shared__ int h[NBUCK];       // counts, then adj (gbase - lscan)
    __shared__ int pos[NBUCK];     // exclusive scan, then bumped during scatter
    __shared__ int partial[256];
    __shared__ int2 stg[EPB];
    const int t = threadIdx.x;
    const int bs = blockIdx.x * EPB;
    const int ce = min(EPB, N_EDGES - bs);

    int sv[16], dv[16];
    #pragma unroll
    for (int i = 0; i < 16; i++) {
        int e = t + i * 256;
        if (e < ce) { sv[i] = ei[bs + e]; dv[i] = ei[N_EDGES + bs + e]; }
        else { sv[i] = 0; dv[i] = -1; }
    }
    for (int i = t; i < NBUCK; i += 256) h[i] = 0;
    __syncthreads();
    #pragma unroll
    for (int i = 0; i < 16; i++)
        if (dv[i] >= 0) atomicAdd(&h[dv[i] >> BSH], 1);
    __syncthreads();

    const int c0 = t * 4;
    int l0 = 0, l1 = 0, l2 = 0, l3 = 0, sum = 0;
    if (c0 < NBUCK) {
        l0 = h[c0]; sum = l0;
        if (c0 + 1 < NBUCK) { l1 = h[c0 + 1]; sum += l1; }
        if (c0 + 2 < NBUCK) { l2 = h[c0 + 2]; sum += l2; }
        if (c0 + 3 < NBUCK) { l3 = h[c0 + 3]; sum += l3; }
    }
    partial[t] = sum;
    __syncthreads();
    for (int off = 1; off < 256; off <<= 1) {
        int u = (t >= off) ? partial[t - off] : 0;
        __syncthreads();
        partial[t] += u;
        __syncthreads();
    }
    int run = partial[t] - sum;
    if (c0 < NBUCK) {
        pos[c0] = run; run += l0;
        if (c0 + 1 < NBUCK) { pos[c0 + 1] = run; run += l1; }
        if (c0 + 2 < NBUCK) { pos[c0 + 2] = run; run += l2; }
        if (c0 + 3 < NBUCK) { pos[c0 + 3] = run; run += l3; }
    }
    __syncthreads();

    for (int b = t; b < NBUCK; b += 256) {
        int cnt = h[b];
        if (cnt > 0) {
            int g = atomicAdd(&bcursor[b], cnt);
            h[b] = g - pos[b];
        }
    }
    __syncthreads();

    #pragma unroll
    for (int i = 0; i < 16; i++) {
        if (dv[i] >= 0) {
            int b = dv[i] >> BSH;
            int p = atomicAdd(&pos[b], 1);
            stg[p] = make_int2(sv[i], dv[i]);
        }
    }
    __syncthreads();

    for (int j = t; j < ce; j += 256) {
        int2 pr = stg[j];
        pairs[j + h[pr.y >> BSH]] =
            ((unsigned int)pr.x << 7) | (unsigned int)(pr.y & (BROWS - 1));
    }
}

// ---------------- per-bucket exact counting sort -> CSR (row_ptr, sorted_src) ----------------

__global__ __launch_bounds__(256) void k_sort(const unsigned int* __restrict__ pairs,
                                              const int* __restrict__ bptr,
                                              int* __restrict__ row_ptr,
                                              int* __restrict__ sorted_src) {
    __shared__ int hist[BROWS];
    __shared__ int pos[BROWS];
    const int t = threadIdx.x;
    const int b = blockIdx.x;
    const int nbase = b << BSH;
    const int start = bptr[b], end = bptr[b + 1];

    if (t < BROWS) hist[t] = 0;
    __syncthreads();
    for (int e = start + t; e < end; e += 256) {
        atomicAdd(&hist[pairs[e] & (BROWS - 1)], 1);
    }
    __syncthreads();
    if (t < BROWS) pos[t] = hist[t];
    __syncthreads();
    for (int off = 1; off < BROWS; off <<= 1) {
        int v = 0;
        if (t < BROWS && t >= off) v = pos[t - off];
        __syncthreads();
        if (t < BROWS) pos[t] += v;
        __syncthreads();
    }
    if (t < BROWS) {
        int rp = start + pos[t] - hist[t];
        int n = nbase + t;
        if (n < N_NODES) row_ptr[n] = rp;
        pos[t] = rp;
    }
    if (b == 0 && t == 0) row_ptr[N_NODES] = N_EDGES;
    __syncthreads();
    for (int e = start + t; e < end; e += 256) {
        unsigned int p = pairs[e];
        int idx = atomicAdd(&pos[p & (BROWS - 1)], 1);
        sorted_src[idx] = (int)(p >> 7);
    }
}

// ---------------- conv1 front: t1 = x@W1 (fp32), t2 = relu(x)@W1 (fp16) ----------------
// 128-row tile, half-K staged; 4 rows x 6 cols per thread (rows rg+32i: LDS
// conflict-free); 60.2 KB LDS -> 2 blocks/CU, 8 waves/CU.

__global__ __launch_bounds__(256) void k_g1(const float* __restrict__ x,
                                            const float* __restrict__ W1,
                                            float* __restrict__ t1,
                                            __half* __restrict__ t2) {
    __shared__ float sX[128 * PADH];   // 34.8 KB (half-K: 64 floats + pad)
    __shared__ float sW[DIM * PADK];   // 25.3 KB, W1^T: [col][k]
    const int t = threadIdx.x;
    const int base = blockIdx.x * 128;

    for (int idx = t; idx < N_FEAT * DIM; idx += 256) {
        int k = idx / DIM, c = idx - k * DIM;
        sW[c * PADK + k] = W1[idx];
    }

    const int cg = t & 7;          // cols cg*6 .. cg*6+5
    const int rg = t >> 3;         // rows rg, rg+32, rg+64, rg+96
    const int c0 = cg * 6;

    float a1[4][6], a2[4][6];
    #pragma unroll
    for (int i = 0; i < 4; i++)
        #pragma unroll
        for (int c = 0; c < 6; c++) { a1[i][c] = 0.f; a2[i][c] = 0.f; }

    for (int h = 0; h < 2; h++) {
        __syncthreads();   // h=0: also covers sW staging; h=1: guard prior reads
        for (int idx = t; idx < 128 * 16; idx += 256) {
            int row = idx >> 4, q = idx & 15;
            float4 v = make_float4(0.f, 0.f, 0.f, 0.f);
            if (base + row < N_NODES) v = ((const float4*)x)[(base + row) * 32 + h * 16 + q];
            *(float4*)&sX[row * PADH + q * 4] = v;
        }
        __syncthreads();

        #pragma unroll 2
        for (int kq = 0; kq < 16; kq++) {
            float4 xr[4], pr[4];
            #pragma unroll
            for (int i = 0; i < 4; i++) {
                xr[i] = *(const float4*)&sX[(rg + 32 * i) * PADH + kq * 4];
                pr[i] = make_float4(fmaxf(xr[i].x, 0.f), fmaxf(xr[i].y, 0.f),
                                    fmaxf(xr[i].z, 0.f), fmaxf(xr[i].w, 0.f));
            }
            #pragma unroll
            for (int c = 0; c < 6; c++) {
                float4 w = *(const float4*)&sW[(c0 + c) * PADK + h * 64 + kq * 4];
                #pragma unroll
                for (int i = 0; i < 4; i++) {
                    a1[i][c] += xr[i].x * w.x + xr[i].y * w.y + xr[i].z * w.z + xr[i].w * w.w;
                    a2[i][c] += pr[i].x * w.x + pr[i].y * w.y + pr[i].z * w.z + pr[i].w * w.w;
                }
            }
        }
    }

    #pragma unroll
    for (int i = 0; i < 4; i++) {
        int gr = base + rg + 32 * i;
        if (gr < N_NODES) {
            #pragma unroll
            for (int c = 0; c < 3; c++) {
                *(float2*)&t1[gr * DIM + c0 + 2 * c] = make_float2(a1[i][2 * c], a1[i][2 * c + 1]);
                *(__half2*)&t2[gr * DIM + c0 + 2 * c] =
                    __float22half2_rn(make_float2(a2[i][2 * c], a2[i][2 * c + 1]));
            }
        }
    }
}

// ---------------- aggregation: out = relu(tlin + segsum(tmsg_fp16) + bias) ----------------
// 5 nodes per wave: 12 lanes per node, each lane gathers 8B (4 halfs) of the
// 96B message row -> one VMEM instruction serves 5 edges.
// out aliases tlin: read-before-write, same thread, row-exclusive.

__device__ inline float2 h2tof2(unsigned int u) {
    __half2 h = *reinterpret_cast<__half2*>(&u);
    return __half22float2(h);
}

__global__ __launch_bounds__(256) void k_aggr(const float* tlin,
                                              const uint2* __restrict__ tmsg8,  // [N][12] 8B chunks
                                              const int* __restrict__ row_ptr,
                                              const int* __restrict__ ssrc,
                                              const float* __restrict__ bias,
                                              float* out) {
    const int t = threadIdx.x;
    const int wid = t >> 6, lane = t & 63;
    const int sub = lane / 12;          // 0..5 (5 == idle lanes 60-63)
    const int fl  = lane - sub * 12;    // 0..11 -> features fl*4 .. fl*4+3
    int n = blockIdx.x * 20 + wid * 5 + sub;
    const bool act = (sub < 5) && (n < N_NODES);
    int start = 0, end = 0;
    if (act) { start = row_ptr[n]; end = row_ptr[n + 1]; }

    float ax = 0.f, ay = 0.f, az = 0.f, aw = 0.f;
    int e = start;
    for (; e + 8 <= end; e += 8) {
        int s0 = ssrc[e], s1 = ssrc[e + 1], s2 = ssrc[e + 2], s3 = ssrc[e + 3];
        int s4 = ssrc[e + 4], s5 = ssrc[e + 5], s6 = ssrc[e + 6], s7 = ssrc[e + 7];
        uint2 v0 = tmsg8[s0 * 12 + fl];
        uint2 v1 = tmsg8[s1 * 12 + fl];
        uint2 v2 = tmsg8[s2 * 12 + fl];
        uint2 v3 = tmsg8[s3 * 12 + fl];
        uint2 v4 = tmsg8[s4 * 12 + fl];
        uint2 v5 = tmsg8[s5 * 12 + fl];
        uint2 v6 = tmsg8[s6 * 12 + fl];
        uint2 v7 = tmsg8[s7 * 12 + fl];
        float2 f;
        f = h2tof2(v0.x); ax += f.x; ay += f.y;  f = h2tof2(v0.y); az += f.x; aw += f.y;
        f = h2tof2(v1.x); ax += f.x; ay += f.y;  f = h2tof2(v1.y); az += f.x; aw += f.y;
        f = h2tof2(v2.x); ax += f.x; ay += f.y;  f = h2tof2(v2.y); az += f.x; aw += f.y;
        f = h2tof2(v3.x); ax += f.x; ay += f.y;  f = h2tof2(v3.y); az += f.x; aw += f.y;
        f = h2tof2(v4.x); ax += f.x; ay += f.y;  f = h2tof2(v4.y); az += f.x; aw += f.y;
        f = h2tof2(v5.x); ax += f.x; ay += f.y;  f = h2tof2(v5.y); az += f.x; aw += f.y;
        f = h2tof2(v6.x); ax += f.x; ay += f.y;  f = h2tof2(v6.y); az += f.x; aw += f.y;
        f = h2tof2(v7.x); ax += f.x; ay += f.y;  f = h2tof2(v7.y); az += f.x; aw += f.y;
    }
    for (; e < end; e++) {
        int s = ssrc[e];
        uint2 v = tmsg8[s * 12 + fl];
        float2 f;
        f = h2tof2(v.x); ax += f.x; ay += f.y;
        f = h2tof2(v.y); az += f.x; aw += f.y;
    }
    if (act) {
        float4 base = ((const float4*)tlin)[n * 12 + fl];
        float4 bi   = ((const float4*)bias)[fl];
        float4 r;
        r.x = fmaxf(base.x + ax + bi.x, 0.f);
        r.y = fmaxf(base.y + ay + bi.y, 0.f);
        r.z = fmaxf(base.z + az + bi.z, 0.f);
        r.w = fmaxf(base.w + aw + bi.w, 0.f);
        ((float4*)out)[n * 12 + fl] = r;
    }
}

// ---------------- chain1: v=u@c1W2+b2; g1=bn1(relu(v)); t3=g1@c2W1 (fp32); t4=relu(g1)@c2W1 (fp16) ----------------
// t3 aliases u: u fully staged to LDS before first sync; writes after; row-exclusive.

__global__ __launch_bounds__(256) void k_chain1(const float* u,
                                                const float* __restrict__ W2,
                                                const float* __restrict__ b2,
                                                const float* __restrict__ bng,
                                                const float* __restrict__ bnb,
                                                const float* __restrict__ bnm,
                                                const float* __restrict__ bnv,
                                                const float* __restrict__ W1n,
                                                float* t3,
                                                __half* __restrict__ t4) {
    __shared__ float sU[64 * PADD];
    __shared__ float sG[64 * PADD];
    __shared__ float sW2[DIM * PADD];
    __shared__ float sW1[DIM * PADD];
    const int t = threadIdx.x;
    const int base = blockIdx.x * 64;

    for (int idx = t; idx < DIM * DIM; idx += 256) {
        int k = idx / DIM, c = idx - k * DIM;
        sW2[c * PADD + k] = W2[idx];
        sW1[c * PADD + k] = W1n[idx];
    }
    for (int idx = t; idx < 64 * 12; idx += 256) {
        int row = idx / 12, kq = idx - row * 12;
        float4 v = make_float4(0.f, 0.f, 0.f, 0.f);
        if (base + row < N_NODES) v = ((const float4*)u)[(base + row) * 12 + kq];
        *(float4*)&sU[row * PADD + kq * 4] = v;
    }
    __syncthreads();

    const int cg = t & 7, rg = t >> 3;
    const int r0 = rg * 2, c0 = cg * 6;

    {
        float g[2][6];
        #pragma unroll
        for (int r = 0; r < 2; r++)
            #pragma unroll
            for (int c = 0; c < 6; c++) g[r][c] = 0.f;

        #pragma unroll 2
        for (int kq = 0; kq < 12; kq++) {
            float4 x0 = *(const float4*)&sU[(r0 + 0) * PADD + kq * 4];
            float4 x1 = *(const float4*)&sU[(r0 + 1) * PADD + kq * 4];
            #pragma unroll
            for (int c = 0; c < 6; c++) {
                float4 w = *(const float4*)&sW2[(c0 + c) * PADD + kq * 4];
                g[0][c] += x0.x * w.x + x0.y * w.y + x0.z * w.z + x0.w * w.w;
                g[1][c] += x1.x * w.x + x1.y * w.y + x1.z * w.z + x1.w * w.w;
            }
        }
        #pragma unroll
        for (int c = 0; c < 6; c++) {
            float bb = b2[c0 + c];
            float sc = bng[c0 + c] * rsqrtf(bnv[c0 + c] + BN_EPS);
            float sh = bnb[c0 + c] - bnm[c0 + c] * sc;
            #pragma unroll
            for (int r = 0; r < 2; r++) {
                float rl = fmaxf(g[r][c] + bb, 0.f);
                sG[(r0 + r) * PADD + c0 + c] = rl * sc + sh;
            }
        }
    }
    __syncthreads();

    {
        float a3[2][6], a4[2][6];
        #pragma unroll
        for (int r = 0; r < 2; r++)
            #pragma unroll
            for (int c = 0; c < 6; c++) { a3[r][c] = 0.f; a4[r][c] = 0.f; }

        #pragma unroll 2
        for (int kq = 0; kq < 12; kq++) {
            float4 x0 = *(const float4*)&sG[(r0 + 0) * PADD + kq * 4];
            float4 x1 = *(const float4*)&sG[(r0 + 1) * PADD + kq * 4];
            float4 p0 = make_float4(fmaxf(x0.x, 0.f), fmaxf(x0.y, 0.f), fmaxf(x0.z, 0.f), fmaxf(x0.w, 0.f));
            float4 p1 = make_float4(fmaxf(x1.x, 0.f), fmaxf(x1.y, 0.f), fmaxf(x1.z, 0.f), fmaxf(x1.w, 0.f));
            #pragma unroll
            for (int c = 0; c < 6; c++) {
                float4 w = *(const float4*)&sW1[(c0 + c) * PADD + kq * 4];
                a3[0][c] += x0.x * w.x + x0.y * w.y + x0.z * w.z + x0.w * w.w;
                a3[1][c] += x1.x * w.x + x1.y * w.y + x1.z * w.z + x1.w * w.w;
                a4[0][c] += p0.x * w.x + p0.y * w.y + p0.z * w.z + p0.w * w.w;
                a4[1][c] += p1.x * w.x + p1.y * w.y + p1.z * w.z + p1.w * w.w;
            }
        }
        #pragma unroll
        for (int r = 0; r < 2; r++) {
            int gr = base + r0 + r;
            if (gr < N_NODES) {
                #pragma unroll
                for (int c = 0; c < 3; c++) {
                    *(float2*)&t3[gr * DIM + c0 + 2 * c] = make_float2(a3[r][2 * c], a3[r][2 * c + 1]);
                    *(__half2*)&t4[gr * DIM + c0 + 2 * c] =
                        __float22half2_rn(make_float2(a4[r][2 * c], a4[r][2 * c + 1]));
                }
            }
        }
    }
}

// ---------------- chain2: v2=u2@c2W2+b2; g2=bn2(relu); z=relu(g2@fc1+b); out=z@fc2+b ----------------

__global__ __launch_bounds__(256) void k_chain2(const float* __restrict__ u2,
                                                const float* __restrict__ W2,
                                                const float* __restrict__ b2,
                                                const float* __restrict__ bng,
                                                const float* __restrict__ bnb,
                                                const float* __restrict__ bnm,
                                                const float* __restrict__ bnv,
                                                const float* __restrict__ fc1W,
                                                const float* __restrict__ fc1b,
                                                const float* __restrict__ fc2W,
                                                const float* __restrict__ fc2b,
                                                float* __restrict__ out) {
    __shared__ float sA[64 * PADD];
    __shared__ float sB[64 * PADD];
    __shared__ float sWa[DIM * PADD];
    __shared__ float sWb[DIM * PADD];
    __shared__ float sWc[N_CLASS * PADD];
    const int t = threadIdx.x;
    const int base = blockIdx.x * 64;

    for (int idx = t; idx < DIM * DIM; idx += 256) {
        int k = idx / DIM, c = idx - k * DIM;
        sWa[c * PADD + k] = W2[idx];
        sWb[c * PADD + k] = fc1W[idx];
    }
    for (int idx = t; idx < DIM * N_CLASS; idx += 256) {
        int k = idx / N_CLASS, c = idx - k * N_CLASS;
        sWc[c * PADD + k] = fc2W[idx];
    }
    for (int idx = t; idx < 64 * 12; idx += 256) {
        int row = idx / 12, kq = idx - row * 12;
        float4 v = make_float4(0.f, 0.f, 0.f, 0.f);
        if (base + row < N_NODES) v = ((const float4*)u2)[(base + row) * 12 + kq];
        *(float4*)&sA[row * PADD + kq * 4] = v;
    }
    __syncthreads();

    const int cg = t & 7, rg = t >> 3;
    const int r0 = rg * 2, c0 = cg * 6;

    {
        float g[2][6];
        #pragma unroll
        for (int r = 0; r < 2; r++)
            #pragma unroll
            for (int c = 0; c < 6; c++) g[r][c] = 0.f;
        #pragma unroll 2
        for (int kq = 0; kq < 12; kq++) {
            float4 x0 = *(const float4*)&sA[(r0 + 0) * PADD + kq * 4];
            float4 x1 = *(const float4*)&sA[(r0 + 1) * PADD + kq * 4];
            #pragma unroll
            for (int c = 0; c < 6; c++) {
                float4 w = *(const float4*)&sWa[(c0 + c) * PADD + kq * 4];
                g[0][c] += x0.x * w.x + x0.y * w.y + x0.z * w.z + x0.w * w.w;
                g[1][c] += x1.x * w.x + x1.y * w.y + x1.z * w.z + x1.w * w.w;
            }
        }
        #pragma unroll
        for (int c = 0; c < 6; c++) {
            float bb = b2[c0 + c];
            float sc = bng[c0 + c] * rsqrtf(bnv[c0 + c] + BN_EPS);
            float sh = bnb[c0 + c] - bnm[c0 + c] * sc;
            #pragma unroll
            for (int r = 0; r < 2; r++) {
                float rl = fmaxf(g[r][c] + bb, 0.f);
                sB[(r0 + r) * PADD + c0 + c] = rl * sc + sh;
            }
        }
    }
    __syncthreads();

    {
        float z[2][6];
        #pragma unroll
        for (int r = 0; r < 2; r++)
            #pragma unroll
            for (int c = 0; c < 6; c++) z[r][c] = 0.f;
        #pragma unroll 2
        for (int kq = 0; kq < 12; kq++) {
            float4 x0 = *(const float4*)&sB[(r0 + 0) * PADD + kq * 4];
            float4 x1 = *(const float4*)&sB[(r0 + 1) * PADD + kq * 4];
            #pragma unroll
            for (int c = 0; c < 6; c++) {
                float4 w = *(const float4*)&sWb[(c0 + c) * PADD + kq * 4];
                z[0][c] += x0.x * w.x + x0.y * w.y + x0.z * w.z + x0.w * w.w;
                z[1][c] += x1.x * w.x + x1.y * w.y + x1.z * w.z + x1.w * w.w;
            }
        }
        __syncthreads();
        #pragma unroll
        for (int c = 0; c < 6; c++) {
            float bb = fc1b[c0 + c];
            #pragma unroll
            for (int r = 0; r < 2; r++)
                sA[(r0 + r) * PADD + c0 + c] = fmaxf(z[r][c] + bb, 0.f);
        }
    }
    __syncthreads();

    if (cg < 6) {
        const int cc0 = cg * 3;
        float o[2][3];
        #pragma unroll
        for (int r = 0; r < 2; r++)
            #pragma unroll
            for (int c = 0; c < 3; c++) o[r][c] = 0.f;
        #pragma unroll 2
        for (int kq = 0; kq < 12; kq++) {
            float4 x0 = *(const float4*)&sA[(r0 + 0) * PADD + kq * 4];
            float4 x1 = *(const float4*)&sA[(r0 + 1) * PADD + kq * 4];
            #pragma unroll
            for (int c = 0; c < 3; c++) {
                float4 w = *(const float4*)&sWc[(cc0 + c) * PADD + kq * 4];
                o[0][c] += x0.x * w.x + x0.y * w.y + x0.z * w.z + x0.w * w.w;
                o[1][c] += x1.x * w.x + x1.y * w.y + x1.z * w.z + x1.w * w.w;
            }
        }
        #pragma unroll
        for (int r = 0; r < 2; r++) {
            int gr = base + r0 + r;
            if (gr < N_NODES) {
                #pragma unroll
                for (int c = 0; c < 3; c++)
                    out[gr * N_CLASS + cc0 + c] = o[r][c] + fc2b[cc0 + c];
            }
        }
    }
}

// ---------------- launch ----------------

extern "C" void kernel_launch(void* const* d_in, const int* in_sizes, int n_in,
                              void* d_out, int out_size, void* d_ws, size_t ws_size,
                              hipStream_t stream) {
    const float* x     = (const float*)d_in[0];
    const int*   ei    = (const int*)d_in[1];
    const float* c1_W1 = (const float*)d_in[2];
    const float* c1_b1 = (const float*)d_in[3];
    const float* c1_W2 = (const float*)d_in[4];
    const float* c1_b2 = (const float*)d_in[5];
    const float* c2_W1 = (const float*)d_in[6];
    const float* c2_b1 = (const float*)d_in[7];
    const float* c2_W2 = (const float*)d_in[8];
    const float* c2_b2 = (const float*)d_in[9];
    const float* bn1_g = (const float*)d_in[10];
    const float* bn1_b = (const float*)d_in[11];
    const float* bn1_m = (const float*)d_in[12];
    const float* bn1_v = (const float*)d_in[13];
    const float* bn2_g = (const float*)d_in[14];
    const float* bn2_b = (const float*)d_in[15];
    const float* bn2_m = (const float*)d_in[16];
    const float* bn2_v = (const float*)d_in[17];
    const float* fc1_W = (const float*)d_in[18];
    const float* fc1_b = (const float*)d_in[19];
    const float* fc2_W = (const float*)d_in[20];
    const float* fc2_b = (const float*)d_in[21];
    float* out = (float*)d_out;

    char* ws = (char*)d_ws;
    size_t o = 0;
    auto take = [&](size_t bytes) {
        void* p = ws + o;
        o = (o + bytes + 255) & ~(size_t)255;
        return p;
    };
    unsigned int* pairs = (unsigned int*)take((size_t)N_EDGES * 4);   // 12.8 MB (packed)
    int*  sorted_src    = (int*)take((size_t)N_EDGES * 4);            // 12.8 MB
    int*  row_ptr       = (int*)take((size_t)(N_NODES + 1) * 4);
    int*  bcnt          = (int*)take((size_t)NBUCK * 4);
    int*  bptr          = (int*)take((size_t)(NBUCK + 1) * 4);
    int*  bcursor       = (int*)take((size_t)NBUCK * 4);
    float*  t1          = (float*)take((size_t)N_NODES * DIM * 4);    // aliased: t1/u/t3/u2 (fp32)
    __half* t2h         = (__half*)take((size_t)N_NODES * DIM * 2);   // t2/t4 (fp16 messages)
    (void)ws_size; (void)in_sizes; (void)n_in; (void)out_size;

    const int NB128 = (N_NODES + 127) / 128;  // 782
    const int NB64  = (N_NODES + 63) / 64;    // 1563
    const int NB20  = (N_NODES + 19) / 20;    // 5000

    hipMemsetAsync(bcnt, 0, (size_t)NBUCK * 4, stream);
    k_bhist<<<NBLK_E, 256, 0, stream>>>(ei, bcnt);
    k_bscan<<<1, 1024, 0, stream>>>(bcnt, bptr, bcursor);
    k_bin<<<NBLK_E, 256, 0, stream>>>(ei, bcursor, pairs);
    k_sort<<<NBUCK, 256, 0, stream>>>(pairs, bptr, row_ptr, sorted_src);

    k_g1<<<NB128, 256, 0, stream>>>(x, c1_W1, t1, t2h);
    k_aggr<<<NB20, 256, 0, stream>>>(t1, (const uint2*)t2h, row_ptr, sorted_src, c1_b1, t1);
    k_chain1<<<NB64, 256, 0, stream>>>(t1, c1_W2, c1_b2, bn1_g, bn1_b, bn1_m, bn1_v,
                                       c2_W1, t1, t2h);
    k_aggr<<<NB20, 256, 0, stream>>>(t1, (const uint2*)t2h, row_ptr, sorted_src, c2_b1, t1);
    k_chain2<<<NB64, 256, 0, stream>>>(t1, c2_W2, c2_b2, bn2_g, bn2_b, bn2_m, bn2_v,
                                       fc1_W, fc1_b, fc2_W, fc2_b, out);
}

// Round 9
// 348.821 us; speedup vs baseline: 1.0168x; 1.0168x over previous
//
#include <hip/hip_runtime.h>
#include <hip/hip_fp16.h>

#define N_NODES 100000
#define N_EDGES 3200000
#define N_FEAT  128
#define DIM     48
#define N_CLASS 18
#define BN_EPS  1e-5f

#define PADK 132   // W^T tile row stride (dwords)
#define PADH 68    // half-K x-tile row stride (dwords)
#define PADD 52    // 48-wide tile row stride

#define BSH    7                                   // bucket = dst >> 7 (128 nodes)
#define BROWS  128                                 // nodes per bucket
#define NBUCK  ((N_NODES + BROWS - 1) / BROWS)     // 782
#define EPB    4096                                // edges per binning block
#define NBLK_E ((N_EDGES + EPB - 1) / EPB)         // 782

// packed edge: (src << 7) | (dst & 127).  src < 2^17, fits 24 bits.

// ---------------- bucket-granular edge preprocessing ----------------

__global__ __launch_bounds__(256) void k_bhist(const int* __restrict__ ei,
                                               int* __restrict__ bcnt) {
    __shared__ int h[NBUCK];
    const int t = threadIdx.x;
    for (int i = t; i < NBUCK; i += 256) h[i] = 0;
    __syncthreads();
    int bs = blockIdx.x * EPB;
    int ce = min(EPB, N_EDGES - bs);
    for (int i = t; i < ce; i += 256) {
        int d = ei[N_EDGES + bs + i];
        atomicAdd(&h[d >> BSH], 1);
    }
    __syncthreads();
    for (int i = t; i < NBUCK; i += 256)
        if (h[i]) atomicAdd(&bcnt[i], h[i]);
}

__global__ __launch_bounds__(1024) void k_bscan(const int* __restrict__ bcnt,
                                                int* __restrict__ bptr,
                                                int* __restrict__ bcursor) {
    __shared__ int s[1024];
    const int t = threadIdx.x;
    int v = (t < NBUCK) ? bcnt[t] : 0;
    s[t] = v;
    __syncthreads();
    for (int off = 1; off < 1024; off <<= 1) {
        int u = (t >= off) ? s[t - off] : 0;
        __syncthreads();
        s[t] += u;
        __syncthreads();
    }
    if (t < NBUCK) {
        int excl = s[t] - v;
        bptr[t] = excl;
        bcursor[t] = excl;
        if (t == NBUCK - 1) bptr[NBUCK] = s[t];
    }
}

// LDS-staged binning: packed pairs written in bucket-contiguous runs,
// one global reserve atomic per (block,bucket).
__global__ __launch_bounds__(256) void k_bin(const int* __restrict__ ei,
                                             int* __restrict__ bcursor,
                                             unsigned int* __restrict__ pairs) {
    __shared__ int h[NBUCK];       // counts, then adj (gbase - lscan)
    __shared__ int pos[NBUCK];     // exclusive scan, then bumped during scatter
    __shared__ int partial[256];
    __shared__ int2 stg[EPB];
    const int t = threadIdx.x;
    const int bs = blockIdx.x * EPB;
    const int ce = min(EPB, N_EDGES - bs);

    int sv[16], dv[16];
    #pragma unroll
    for (int i = 0; i < 16; i++) {
        int e = t + i * 256;
        if (e < ce) { sv[i] = ei[bs + e]; dv[i] = ei[N_EDGES + bs + e]; }
        else { sv[i] = 0; dv[i] = -1; }
    }
    for (int i = t; i < NBUCK; i += 256) h[i] = 0;
    __syncthreads();
    #pragma unroll
    for (int i = 0; i < 16; i++)
        if (dv[i] >= 0) atomicAdd(&h[dv[i] >> BSH], 1);
    __syncthreads();

    const int c0 = t * 4;
    int l0 = 0, l1 = 0, l2 = 0, l3 = 0, sum = 0;
    if (c0 < NBUCK) {
        l0 = h[c0]; sum = l0;
        if (c0 + 1 < NBUCK) { l1 = h[c0 + 1]; sum += l1; }
        if (c0 + 2 < NBUCK) { l2 = h[c0 + 2]; sum += l2; }
        if (c0 + 3 < NBUCK) { l3 = h[c0 + 3]; sum += l3; }
    }
    partial[t] = sum;
    __syncthreads();
    for (int off = 1; off < 256; off <<= 1) {
        int u = (t >= off) ? partial[t - off] : 0;
        __syncthreads();
        partial[t] += u;
        __syncthreads();
    }
    int run = partial[t] - sum;
    if (c0 < NBUCK) {
        pos[c0] = run; run += l0;
        if (c0 + 1 < NBUCK) { pos[c0 + 1] = run; run += l1; }
        if (c0 + 2 < NBUCK) { pos[c0 + 2] = run; run += l2; }
        if (c0 + 3 < NBUCK) { pos[c0 + 3] = run; run += l3; }
    }
    __syncthreads();

    for (int b = t; b < NBUCK; b += 256) {
        int cnt = h[b];
        if (cnt > 0) {
            int g = atomicAdd(&bcursor[b], cnt);
            h[b] = g - pos[b];
        }
    }
    __syncthreads();

    #pragma unroll
    for (int i = 0; i < 16; i++) {
        if (dv[i] >= 0) {
            int b = dv[i] >> BSH;
            int p = atomicAdd(&pos[b], 1);
            stg[p] = make_int2(sv[i], dv[i]);
        }
    }
    __syncthreads();

    for (int j = t; j < ce; j += 256) {
        int2 pr = stg[j];
        pairs[j + h[pr.y >> BSH]] =
            ((unsigned int)pr.x << 7) | (unsigned int)(pr.y & (BROWS - 1));
    }
}

// ---------------- per-bucket exact counting sort -> CSR (row_ptr, sorted_src) ----------------

__global__ __launch_bounds__(256) void k_sort(const unsigned int* __restrict__ pairs,
                                              const int* __restrict__ bptr,
                                              int* __restrict__ row_ptr,
                                              int* __restrict__ sorted_src) {
    __shared__ int hist[BROWS];
    __shared__ int pos[BROWS];
    const int t = threadIdx.x;
    const int b = blockIdx.x;
    const int nbase = b << BSH;
    const int start = bptr[b], end = bptr[b + 1];

    if (t < BROWS) hist[t] = 0;
    __syncthreads();
    for (int e = start + t; e < end; e += 256) {
        atomicAdd(&hist[pairs[e] & (BROWS - 1)], 1);
    }
    __syncthreads();
    if (t < BROWS) pos[t] = hist[t];
    __syncthreads();
    for (int off = 1; off < BROWS; off <<= 1) {
        int v = 0;
        if (t < BROWS && t >= off) v = pos[t - off];
        __syncthreads();
        if (t < BROWS) pos[t] += v;
        __syncthreads();
    }
    if (t < BROWS) {
        int rp = start + pos[t] - hist[t];
        int n = nbase + t;
        if (n < N_NODES) row_ptr[n] = rp;
        pos[t] = rp;
    }
    if (b == 0 && t == 0) row_ptr[N_NODES] = N_EDGES;
    __syncthreads();
    for (int e = start + t; e < end; e += 256) {
        unsigned int p = pairs[e];
        int idx = atomicAdd(&pos[p & (BROWS - 1)], 1);
        sorted_src[idx] = (int)(p >> 7);
    }
}

// ---------------- conv1 front: t1 = x@W1 (fp32), t2 = relu(x)@W1 (fp16) ----------------
// 64-row tile, 2 rows x 6 cols per thread (R7 structure), but x staged in two
// K=64 halves: LDS 42.8 KB -> 3 blocks/CU (was 2). VGPR stays ~88.

__global__ __launch_bounds__(256) void k_g1(const float* __restrict__ x,
                                            const float* __restrict__ W1,
                                            float* __restrict__ t1,
                                            __half* __restrict__ t2) {
    __shared__ float sX[64 * PADH];    // 17.4 KB (half-K: 64 floats + pad)
    __shared__ float sW[DIM * PADK];   // 25.3 KB, W1^T: [col][k]
    const int t = threadIdx.x;
    const int base = blockIdx.x * 64;

    for (int idx = t; idx < N_FEAT * DIM; idx += 256) {
        int k = idx / DIM, c = idx - k * DIM;
        sW[c * PADK + k] = W1[idx];
    }

    const int cg = t & 7;          // cols cg*6 .. cg*6+5
    const int rg = t >> 3;         // rows rg*2, rg*2+1
    const int r0 = rg * 2;
    const int c0 = cg * 6;

    float a1[2][6], a2[2][6];
    #pragma unroll
    for (int r = 0; r < 2; r++)
        #pragma unroll
        for (int c = 0; c < 6; c++) { a1[r][c] = 0.f; a2[r][c] = 0.f; }

    for (int h = 0; h < 2; h++) {
        __syncthreads();   // h=0: covers sW staging; h=1: guard prior sX reads
        for (int idx = t; idx < 64 * 16; idx += 256) {
            int row = idx >> 4, q = idx & 15;
            float4 v = make_float4(0.f, 0.f, 0.f, 0.f);
            if (base + row < N_NODES) v = ((const float4*)x)[(base + row) * 32 + h * 16 + q];
            *(float4*)&sX[row * PADH + q * 4] = v;
        }
        __syncthreads();

        #pragma unroll 2
        for (int kq = 0; kq < 16; kq++) {
            float4 x0 = *(const float4*)&sX[(r0 + 0) * PADH + kq * 4];
            float4 x1 = *(const float4*)&sX[(r0 + 1) * PADH + kq * 4];
            float4 p0 = make_float4(fmaxf(x0.x, 0.f), fmaxf(x0.y, 0.f), fmaxf(x0.z, 0.f), fmaxf(x0.w, 0.f));
            float4 p1 = make_float4(fmaxf(x1.x, 0.f), fmaxf(x1.y, 0.f), fmaxf(x1.z, 0.f), fmaxf(x1.w, 0.f));
            #pragma unroll
            for (int c = 0; c < 6; c++) {
                float4 w = *(const float4*)&sW[(c0 + c) * PADK + h * 64 + kq * 4];
                a1[0][c] += x0.x * w.x + x0.y * w.y + x0.z * w.z + x0.w * w.w;
                a1[1][c] += x1.x * w.x + x1.y * w.y + x1.z * w.z + x1.w * w.w;
                a2[0][c] += p0.x * w.x + p0.y * w.y + p0.z * w.z + p0.w * w.w;
                a2[1][c] += p1.x * w.x + p1.y * w.y + p1.z * w.z + p1.w * w.w;
            }
        }
    }

    #pragma unroll
    for (int r = 0; r < 2; r++) {
        int gr = base + r0 + r;
        if (gr < N_NODES) {
            #pragma unroll
            for (int c = 0; c < 3; c++) {
                *(float2*)&t1[gr * DIM + c0 + 2 * c] = make_float2(a1[r][2 * c], a1[r][2 * c + 1]);
                *(__half2*)&t2[gr * DIM + c0 + 2 * c] =
                    __float22half2_rn(make_float2(a2[r][2 * c], a2[r][2 * c + 1]));
            }
        }
    }
}

// ---------------- aggregation: out = relu(tlin + segsum(tmsg_fp16) + bias) ----------------
// 5 nodes per wave: 12 lanes per node, each lane gathers 8B (4 halfs) of the
// 96B message row -> one VMEM instruction serves 5 edges.
// out aliases tlin: read-before-write, same thread, row-exclusive.

__device__ inline float2 h2tof2(unsigned int u) {
    __half2 h = *reinterpret_cast<__half2*>(&u);
    return __half22float2(h);
}

__global__ __launch_bounds__(256) void k_aggr(const float* tlin,
                                              const uint2* __restrict__ tmsg8,  // [N][12] 8B chunks
                                              const int* __restrict__ row_ptr,
                                              const int* __restrict__ ssrc,
                                              const float* __restrict__ bias,
                                              float* out) {
    const int t = threadIdx.x;
    const int wid = t >> 6, lane = t & 63;
    const int sub = lane / 12;          // 0..5 (5 == idle lanes 60-63)
    const int fl  = lane - sub * 12;    // 0..11 -> features fl*4 .. fl*4+3
    int n = blockIdx.x * 20 + wid * 5 + sub;
    const bool act = (sub < 5) && (n < N_NODES);
    int start = 0, end = 0;
    if (act) { start = row_ptr[n]; end = row_ptr[n + 1]; }

    float ax = 0.f, ay = 0.f, az = 0.f, aw = 0.f;
    int e = start;
    for (; e + 8 <= end; e += 8) {
        int s0 = ssrc[e], s1 = ssrc[e + 1], s2 = ssrc[e + 2], s3 = ssrc[e + 3];
        int s4 = ssrc[e + 4], s5 = ssrc[e + 5], s6 = ssrc[e + 6], s7 = ssrc[e + 7];
        uint2 v0 = tmsg8[s0 * 12 + fl];
        uint2 v1 = tmsg8[s1 * 12 + fl];
        uint2 v2 = tmsg8[s2 * 12 + fl];
        uint2 v3 = tmsg8[s3 * 12 + fl];
        uint2 v4 = tmsg8[s4 * 12 + fl];
        uint2 v5 = tmsg8[s5 * 12 + fl];
        uint2 v6 = tmsg8[s6 * 12 + fl];
        uint2 v7 = tmsg8[s7 * 12 + fl];
        float2 f;
        f = h2tof2(v0.x); ax += f.x; ay += f.y;  f = h2tof2(v0.y); az += f.x; aw += f.y;
        f = h2tof2(v1.x); ax += f.x; ay += f.y;  f = h2tof2(v1.y); az += f.x; aw += f.y;
        f = h2tof2(v2.x); ax += f.x; ay += f.y;  f = h2tof2(v2.y); az += f.x; aw += f.y;
        f = h2tof2(v3.x); ax += f.x; ay += f.y;  f = h2tof2(v3.y); az += f.x; aw += f.y;
        f = h2tof2(v4.x); ax += f.x; ay += f.y;  f = h2tof2(v4.y); az += f.x; aw += f.y;
        f = h2tof2(v5.x); ax += f.x; ay += f.y;  f = h2tof2(v5.y); az += f.x; aw += f.y;
        f = h2tof2(v6.x); ax += f.x; ay += f.y;  f = h2tof2(v6.y); az += f.x; aw += f.y;
        f = h2tof2(v7.x); ax += f.x; ay += f.y;  f = h2tof2(v7.y); az += f.x; aw += f.y;
    }
    for (; e < end; e++) {
        int s = ssrc[e];
        uint2 v = tmsg8[s * 12 + fl];
        float2 f;
        f = h2tof2(v.x); ax += f.x; ay += f.y;
        f = h2tof2(v.y); az += f.x; aw += f.y;
    }
    if (act) {
        float4 base = ((const float4*)tlin)[n * 12 + fl];
        float4 bi   = ((const float4*)bias)[fl];
        float4 r;
        r.x = fmaxf(base.x + ax + bi.x, 0.f);
        r.y = fmaxf(base.y + ay + bi.y, 0.f);
        r.z = fmaxf(base.z + az + bi.z, 0.f);
        r.w = fmaxf(base.w + aw + bi.w, 0.f);
        ((float4*)out)[n * 12 + fl] = r;
    }
}

// ---------------- chain1: v=u@c1W2+b2; g1=bn1(relu(v)); t3=g1@c2W1 (fp32); t4=relu(g1)@c2W1 (fp16) ----------------
// t3 aliases u: u fully staged to LDS before first sync; writes after; row-exclusive.

__global__ __launch_bounds__(256) void k_chain1(const float* u,
                                                const float* __restrict__ W2,
                                                const float* __restrict__ b2,
                                                const float* __restrict__ bng,
                                                const float* __restrict__ bnb,
                                                const float* __restrict__ bnm,
                                                const float* __restrict__ bnv,
                                                const float* __restrict__ W1n,
                                                float* t3,
                                                __half* __restrict__ t4) {
    __shared__ float sU[64 * PADD];
    __shared__ float sG[64 * PADD];
    __shared__ float sW2[DIM * PADD];
    __shared__ float sW1[DIM * PADD];
    const int t = threadIdx.x;
    const int base = blockIdx.x * 64;

    for (int idx = t; idx < DIM * DIM; idx += 256) {
        int k = idx / DIM, c = idx - k * DIM;
        sW2[c * PADD + k] = W2[idx];
        sW1[c * PADD + k] = W1n[idx];
    }
    for (int idx = t; idx < 64 * 12; idx += 256) {
        int row = idx / 12, kq = idx - row * 12;
        float4 v = make_float4(0.f, 0.f, 0.f, 0.f);
        if (base + row < N_NODES) v = ((const float4*)u)[(base + row) * 12 + kq];
        *(float4*)&sU[row * PADD + kq * 4] = v;
    }
    __syncthreads();

    const int cg = t & 7, rg = t >> 3;
    const int r0 = rg * 2, c0 = cg * 6;

    {
        float g[2][6];
        #pragma unroll
        for (int r = 0; r < 2; r++)
            #pragma unroll
            for (int c = 0; c < 6; c++) g[r][c] = 0.f;

        #pragma unroll 2
        for (int kq = 0; kq < 12; kq++) {
            float4 x0 = *(const float4*)&sU[(r0 + 0) * PADD + kq * 4];
            float4 x1 = *(const float4*)&sU[(r0 + 1) * PADD + kq * 4];
            #pragma unroll
            for (int c = 0; c < 6; c++) {
                float4 w = *(const float4*)&sW2[(c0 + c) * PADD + kq * 4];
                g[0][c] += x0.x * w.x + x0.y * w.y + x0.z * w.z + x0.w * w.w;
                g[1][c] += x1.x * w.x + x1.y * w.y + x1.z * w.z + x1.w * w.w;
            }
        }
        #pragma unroll
        for (int c = 0; c < 6; c++) {
            float bb = b2[c0 + c];
            float sc = bng[c0 + c] * rsqrtf(bnv[c0 + c] + BN_EPS);
            float sh = bnb[c0 + c] - bnm[c0 + c] * sc;
            #pragma unroll
            for (int r = 0; r < 2; r++) {
                float rl = fmaxf(g[r][c] + bb, 0.f);
                sG[(r0 + r) * PADD + c0 + c] = rl * sc + sh;
            }
        }
    }
    __syncthreads();

    {
        float a3[2][6], a4[2][6];
        #pragma unroll
        for (int r = 0; r < 2; r++)
            #pragma unroll
            for (int c = 0; c < 6; c++) { a3[r][c] = 0.f; a4[r][c] = 0.f; }

        #pragma unroll 2
        for (int kq = 0; kq < 12; kq++) {
            float4 x0 = *(const float4*)&sG[(r0 + 0) * PADD + kq * 4];
            float4 x1 = *(const float4*)&sG[(r0 + 1) * PADD + kq * 4];
            float4 p0 = make_float4(fmaxf(x0.x, 0.f), fmaxf(x0.y, 0.f), fmaxf(x0.z, 0.f), fmaxf(x0.w, 0.f));
            float4 p1 = make_float4(fmaxf(x1.x, 0.f), fmaxf(x1.y, 0.f), fmaxf(x1.z, 0.f), fmaxf(x1.w, 0.f));
            #pragma unroll
            for (int c = 0; c < 6; c++) {
                float4 w = *(const float4*)&sW1[(c0 + c) * PADD + kq * 4];
                a3[0][c] += x0.x * w.x + x0.y * w.y + x0.z * w.z + x0.w * w.w;
                a3[1][c] += x1.x * w.x + x1.y * w.y + x1.z * w.z + x1.w * w.w;
                a4[0][c] += p0.x * w.x + p0.y * w.y + p0.z * w.z + p0.w * w.w;
                a4[1][c] += p1.x * w.x + p1.y * w.y + p1.z * w.z + p1.w * w.w;
            }
        }
        #pragma unroll
        for (int r = 0; r < 2; r++) {
            int gr = base + r0 + r;
            if (gr < N_NODES) {
                #pragma unroll
                for (int c = 0; c < 3; c++) {
                    *(float2*)&t3[gr * DIM + c0 + 2 * c] = make_float2(a3[r][2 * c], a3[r][2 * c + 1]);
                    *(__half2*)&t4[gr * DIM + c0 + 2 * c] =
                        __float22half2_rn(make_float2(a4[r][2 * c], a4[r][2 * c + 1]));
                }
            }
        }
    }
}

// ---------------- chain2: v2=u2@c2W2+b2; g2=bn2(relu); z=relu(g2@fc1+b); out=z@fc2+b ----------------

__global__ __launch_bounds__(256) void k_chain2(const float* __restrict__ u2,
                                                const float* __restrict__ W2,
                                                const float* __restrict__ b2,
                                                const float* __restrict__ bng,
                                                const float* __restrict__ bnb,
                                                const float* __restrict__ bnm,
                                                const float* __restrict__ bnv,
                                                const float* __restrict__ fc1W,
                                                const float* __restrict__ fc1b,
                                                const float* __restrict__ fc2W,
                                                const float* __restrict__ fc2b,
                                                float* __restrict__ out) {
    __shared__ float sA[64 * PADD];
    __shared__ float sB[64 * PADD];
    __shared__ float sWa[DIM * PADD];
    __shared__ float sWb[DIM * PADD];
    __shared__ float sWc[N_CLASS * PADD];
    const int t = threadIdx.x;
    const int base = blockIdx.x * 64;

    for (int idx = t; idx < DIM * DIM; idx += 256) {
        int k = idx / DIM, c = idx - k * DIM;
        sWa[c * PADD + k] = W2[idx];
        sWb[c * PADD + k] = fc1W[idx];
    }
    for (int idx = t; idx < DIM * N_CLASS; idx += 256) {
        int k = idx / N_CLASS, c = idx - k * N_CLASS;
        sWc[c * PADD + k] = fc2W[idx];
    }
    for (int idx = t; idx < 64 * 12; idx += 256) {
        int row = idx / 12, kq = idx - row * 12;
        float4 v = make_float4(0.f, 0.f, 0.f, 0.f);
        if (base + row < N_NODES) v = ((const float4*)u2)[(base + row) * 12 + kq];
        *(float4*)&sA[row * PADD + kq * 4] = v;
    }
    __syncthreads();

    const int cg = t & 7, rg = t >> 3;
    const int r0 = rg * 2, c0 = cg * 6;

    {
        float g[2][6];
        #pragma unroll
        for (int r = 0; r < 2; r++)
            #pragma unroll
            for (int c = 0; c < 6; c++) g[r][c] = 0.f;
        #pragma unroll 2
        for (int kq = 0; kq < 12; kq++) {
            float4 x0 = *(const float4*)&sA[(r0 + 0) * PADD + kq * 4];
            float4 x1 = *(const float4*)&sA[(r0 + 1) * PADD + kq * 4];
            #pragma unroll
            for (int c = 0; c < 6; c++) {
                float4 w = *(const float4*)&sWa[(c0 + c) * PADD + kq * 4];
                g[0][c] += x0.x * w.x + x0.y * w.y + x0.z * w.z + x0.w * w.w;
                g[1][c] += x1.x * w.x + x1.y * w.y + x1.z * w.z + x1.w * w.w;
            }
        }
        #pragma unroll
        for (int c = 0; c < 6; c++) {
            float bb = b2[c0 + c];
            float sc = bng[c0 + c] * rsqrtf(bnv[c0 + c] + BN_EPS);
            float sh = bnb[c0 + c] - bnm[c0 + c] * sc;
            #pragma unroll
            for (int r = 0; r < 2; r++) {
                float rl = fmaxf(g[r][c] + bb, 0.f);
                sB[(r0 + r) * PADD + c0 + c] = rl * sc + sh;
            }
        }
    }
    __syncthreads();

    {
        float z[2][6];
        #pragma unroll
        for (int r = 0; r < 2; r++)
            #pragma unroll
            for (int c = 0; c < 6; c++) z[r][c] = 0.f;
        #pragma unroll 2
        for (int kq = 0; kq < 12; kq++) {
            float4 x0 = *(const float4*)&sB[(r0 + 0) * PADD + kq * 4];
            float4 x1 = *(const float4*)&sB[(r0 + 1) * PADD + kq * 4];
            #pragma unroll
            for (int c = 0; c < 6; c++) {
                float4 w = *(const float4*)&sWb[(c0 + c) * PADD + kq * 4];
                z[0][c] += x0.x * w.x + x0.y * w.y + x0.z * w.z + x0.w * w.w;
                z[1][c] += x1.x * w.x + x1.y * w.y + x1.z * w.z + x1.w * w.w;
            }
        }
        __syncthreads();
        #pragma unroll
        for (int c = 0; c < 6; c++) {
            float bb = fc1b[c0 + c];
            #pragma unroll
            for (int r = 0; r < 2; r++)
                sA[(r0 + r) * PADD + c0 + c] = fmaxf(z[r][c] + bb, 0.f);
        }
    }
    __syncthreads();

    if (cg < 6) {
        const int cc0 = cg * 3;
        float o[2][3];
        #pragma unroll
        for (int r = 0; r < 2; r++)
            #pragma unroll
            for (int c = 0; c < 3; c++) o[r][c] = 0.f;
        #pragma unroll 2
        for (int kq = 0; kq < 12; kq++) {
            float4 x0 = *(const float4*)&sA[(r0 + 0) * PADD + kq * 4];
            float4 x1 = *(const float4*)&sA[(r0 + 1) * PADD + kq * 4];
            #pragma unroll
            for (int c = 0; c < 3; c++) {
                float4 w = *(const float4*)&sWc[(cc0 + c) * PADD + kq * 4];
                o[0][c] += x0.x * w.x + x0.y * w.y + x0.z * w.z + x0.w * w.w;
                o[1][c] += x1.x * w.x + x1.y * w.y + x1.z * w.z + x1.w * w.w;
            }
        }
        #pragma unroll
        for (int r = 0; r < 2; r++) {
            int gr = base + r0 + r;
            if (gr < N_NODES) {
                #pragma unroll
                for (int c = 0; c < 3; c++)
                    out[gr * N_CLASS + cc0 + c] = o[r][c] + fc2b[cc0 + c];
            }
        }
    }
}

// ---------------- launch ----------------

extern "C" void kernel_launch(void* const* d_in, const int* in_sizes, int n_in,
                              void* d_out, int out_size, void* d_ws, size_t ws_size,
                              hipStream_t stream) {
    const float* x     = (const float*)d_in[0];
    const int*   ei    = (const int*)d_in[1];
    const float* c1_W1 = (const float*)d_in[2];
    const float* c1_b1 = (const float*)d_in[3];
    const float* c1_W2 = (const float*)d_in[4];
    const float* c1_b2 = (const float*)d_in[5];
    const float* c2_W1 = (const float*)d_in[6];
    const float* c2_b1 = (const float*)d_in[7];
    const float* c2_W2 = (const float*)d_in[8];
    const float* c2_b2 = (const float*)d_in[9];
    const float* bn1_g = (const float*)d_in[10];
    const float* bn1_b = (const float*)d_in[11];
    const float* bn1_m = (const float*)d_in[12];
    const float* bn1_v = (const float*)d_in[13];
    const float* bn2_g = (const float*)d_in[14];
    const float* bn2_b = (const float*)d_in[15];
    const float* bn2_m = (const float*)d_in[16];
    const float* bn2_v = (const float*)d_in[17];
    const float* fc1_W = (const float*)d_in[18];
    const float* fc1_b = (const float*)d_in[19];
    const float* fc2_W = (const float*)d_in[20];
    const float* fc2_b = (const float*)d_in[21];
    float* out = (float*)d_out;

    char* ws = (char*)d_ws;
    size_t o = 0;
    auto take = [&](size_t bytes) {
        void* p = ws + o;
        o = (o + bytes + 255) & ~(size_t)255;
        return p;
    };
    unsigned int* pairs = (unsigned int*)take((size_t)N_EDGES * 4);   // 12.8 MB (packed)
    int*  sorted_src    = (int*)take((size_t)N_EDGES * 4);            // 12.8 MB
    int*  row_ptr       = (int*)take((size_t)(N_NODES + 1) * 4);
    int*  bcnt          = (int*)take((size_t)NBUCK * 4);
    int*  bptr          = (int*)take((size_t)(NBUCK + 1) * 4);
    int*  bcursor       = (int*)take((size_t)NBUCK * 4);
    float*  t1          = (float*)take((size_t)N_NODES * DIM * 4);    // aliased: t1/u/t3/u2 (fp32)
    __half* t2h         = (__half*)take((size_t)N_NODES * DIM * 2);   // t2/t4 (fp16 messages)
    (void)ws_size; (void)in_sizes; (void)n_in; (void)out_size;

    const int NB64 = (N_NODES + 63) / 64;    // 1563
    const int NB20 = (N_NODES + 19) / 20;    // 5000

    hipMemsetAsync(bcnt, 0, (size_t)NBUCK * 4, stream);
    k_bhist<<<NBLK_E, 256, 0, stream>>>(ei, bcnt);
    k_bscan<<<1, 1024, 0, stream>>>(bcnt, bptr, bcursor);
    k_bin<<<NBLK_E, 256, 0, stream>>>(ei, bcursor, pairs);
    k_sort<<<NBUCK, 256, 0, stream>>>(pairs, bptr, row_ptr, sorted_src);

    k_g1<<<NB64, 256, 0, stream>>>(x, c1_W1, t1, t2h);
    k_aggr<<<NB20, 256, 0, stream>>>(t1, (const uint2*)t2h, row_ptr, sorted_src, c1_b1, t1);
    k_chain1<<<NB64, 256, 0, stream>>>(t1, c1_W2, c1_b2, bn1_g, bn1_b, bn1_m, bn1_v,
                                       c2_W1, t1, t2h);
    k_aggr<<<NB20, 256, 0, stream>>>(t1, (const uint2*)t2h, row_ptr, sorted_src, c2_b1, t1);
    k_chain2<<<NB64, 256, 0, stream>>>(t1, c2_W2, c2_b2, bn2_g, bn2_b, bn2_m, bn2_v,
                                       fc1_W, fc1_b, fc2_W, fc2_b, out);
}

// Round 10
// 328.994 us; speedup vs baseline: 1.0781x; 1.0603x over previous
//
#include <hip/hip_runtime.h>
#include <hip/hip_fp16.h>

#define N_NODES 100000
#define N_EDGES 3200000
#define N_FEAT  128
#define DIM     48
#define N_CLASS 18
#define BN_EPS  1e-5f

#define PADW 136   // f16 MFMA tile row stride (272 B): 2-way bank alias only (free)
#define PADD 52    // 48-wide fp32 tile row stride

#define BSH    7                                   // bucket = dst >> 7 (128 nodes)
#define BROWS  128                                 // nodes per bucket
#define NBUCK  ((N_NODES + BROWS - 1) / BROWS)     // 782
#define EPB    4096                                // edges per binning block
#define NBLK_E ((N_EDGES + EPB - 1) / EPB)         // 782

typedef __attribute__((ext_vector_type(8))) _Float16 f16x8;
typedef __attribute__((ext_vector_type(4))) float f32x4;

// packed edge: (src << 7) | (dst & 127).  src < 2^17, fits 24 bits.

// ---------------- bucket-granular edge preprocessing ----------------

__global__ __launch_bounds__(256) void k_bhist(const int* __restrict__ ei,
                                               int* __restrict__ bcnt) {
    __shared__ int h[NBUCK];
    const int t = threadIdx.x;
    for (int i = t; i < NBUCK; i += 256) h[i] = 0;
    __syncthreads();
    int bs = blockIdx.x * EPB;
    int ce = min(EPB, N_EDGES - bs);
    for (int i = t; i < ce; i += 256) {
        int d = ei[N_EDGES + bs + i];
        atomicAdd(&h[d >> BSH], 1);
    }
    __syncthreads();
    for (int i = t; i < NBUCK; i += 256)
        if (h[i]) atomicAdd(&bcnt[i], h[i]);
}

__global__ __launch_bounds__(1024) void k_bscan(const int* __restrict__ bcnt,
                                                int* __restrict__ bptr,
                                                int* __restrict__ bcursor) {
    __shared__ int s[1024];
    const int t = threadIdx.x;
    int v = (t < NBUCK) ? bcnt[t] : 0;
    s[t] = v;
    __syncthreads();
    for (int off = 1; off < 1024; off <<= 1) {
        int u = (t >= off) ? s[t - off] : 0;
        __syncthreads();
        s[t] += u;
        __syncthreads();
    }
    if (t < NBUCK) {
        int excl = s[t] - v;
        bptr[t] = excl;
        bcursor[t] = excl;
        if (t == NBUCK - 1) bptr[NBUCK] = s[t];
    }
}

// LDS-staged binning: packed pairs written in bucket-contiguous runs,
// one global reserve atomic per (block,bucket).
__global__ __launch_bounds__(256) void k_bin(const int* __restrict__ ei,
                                             int* __restrict__ bcursor,
                                             unsigned int* __restrict__ pairs) {
    __shared__ int h[NBUCK];       // counts, then adj (gbase - lscan)
    __shared__ int pos[NBUCK];     // exclusive scan, then bumped during scatter
    __shared__ int partial[256];
    __shared__ int2 stg[EPB];
    const int t = threadIdx.x;
    const int bs = blockIdx.x * EPB;
    const int ce = min(EPB, N_EDGES - bs);

    int sv[16], dv[16];
    #pragma unroll
    for (int i = 0; i < 16; i++) {
        int e = t + i * 256;
        if (e < ce) { sv[i] = ei[bs + e]; dv[i] = ei[N_EDGES + bs + e]; }
        else { sv[i] = 0; dv[i] = -1; }
    }
    for (int i = t; i < NBUCK; i += 256) h[i] = 0;
    __syncthreads();
    #pragma unroll
    for (int i = 0; i < 16; i++)
        if (dv[i] >= 0) atomicAdd(&h[dv[i] >> BSH], 1);
    __syncthreads();

    const int c0 = t * 4;
    int l0 = 0, l1 = 0, l2 = 0, l3 = 0, sum = 0;
    if (c0 < NBUCK) {
        l0 = h[c0]; sum = l0;
        if (c0 + 1 < NBUCK) { l1 = h[c0 + 1]; sum += l1; }
        if (c0 + 2 < NBUCK) { l2 = h[c0 + 2]; sum += l2; }
        if (c0 + 3 < NBUCK) { l3 = h[c0 + 3]; sum += l3; }
    }
    partial[t] = sum;
    __syncthreads();
    for (int off = 1; off < 256; off <<= 1) {
        int u = (t >= off) ? partial[t - off] : 0;
        __syncthreads();
        partial[t] += u;
        __syncthreads();
    }
    int run = partial[t] - sum;
    if (c0 < NBUCK) {
        pos[c0] = run; run += l0;
        if (c0 + 1 < NBUCK) { pos[c0 + 1] = run; run += l1; }
        if (c0 + 2 < NBUCK) { pos[c0 + 2] = run; run += l2; }
        if (c0 + 3 < NBUCK) { pos[c0 + 3] = run; run += l3; }
    }
    __syncthreads();

    for (int b = t; b < NBUCK; b += 256) {
        int cnt = h[b];
        if (cnt > 0) {
            int g = atomicAdd(&bcursor[b], cnt);
            h[b] = g - pos[b];
        }
    }
    __syncthreads();

    #pragma unroll
    for (int i = 0; i < 16; i++) {
        if (dv[i] >= 0) {
            int b = dv[i] >> BSH;
            int p = atomicAdd(&pos[b], 1);
            stg[p] = make_int2(sv[i], dv[i]);
        }
    }
    __syncthreads();

    for (int j = t; j < ce; j += 256) {
        int2 pr = stg[j];
        pairs[j + h[pr.y >> BSH]] =
            ((unsigned int)pr.x << 7) | (unsigned int)(pr.y & (BROWS - 1));
    }
}

// ---------------- per-bucket exact counting sort -> CSR (row_ptr, sorted_src) ----------------

__global__ __launch_bounds__(256) void k_sort(const unsigned int* __restrict__ pairs,
                                              const int* __restrict__ bptr,
                                              int* __restrict__ row_ptr,
                                              int* __restrict__ sorted_src) {
    __shared__ int hist[BROWS];
    __shared__ int pos[BROWS];
    const int t = threadIdx.x;
    const int b = blockIdx.x;
    const int nbase = b << BSH;
    const int start = bptr[b], end = bptr[b + 1];

    if (t < BROWS) hist[t] = 0;
    __syncthreads();
    for (int e = start + t; e < end; e += 256) {
        atomicAdd(&hist[pairs[e] & (BROWS - 1)], 1);
    }
    __syncthreads();
    if (t < BROWS) pos[t] = hist[t];
    __syncthreads();
    for (int off = 1; off < BROWS; off <<= 1) {
        int v = 0;
        if (t < BROWS && t >= off) v = pos[t - off];
        __syncthreads();
        if (t < BROWS) pos[t] += v;
        __syncthreads();
    }
    if (t < BROWS) {
        int rp = start + pos[t] - hist[t];
        int n = nbase + t;
        if (n < N_NODES) row_ptr[n] = rp;
        pos[t] = rp;
    }
    if (b == 0 && t == 0) row_ptr[N_NODES] = N_EDGES;
    __syncthreads();
    for (int e = start + t; e < end; e += 256) {
        unsigned int p = pairs[e];
        int idx = atomicAdd(&pos[p & (BROWS - 1)], 1);
        sorted_src[idx] = (int)(p >> 7);
    }
}

// ---------------- conv1 front (MFMA): t1 = x@W1 (fp32), t2 = relu(x)@W1 (fp16) ----------------
// 64 rows/block, 4 waves; each wave: one 16-row stripe x 48 cols, dual acc
// (t1, t2 with relu applied to the A-fragment in-register, B shared).
// Fragment maps (m89-verified): A row=lane&15, k=(lane>>4)*8+j; B col=lane&15
// (W staged transposed [col][k]); D col=lane&15, row=(lane>>4)*4+reg.

__global__ __launch_bounds__(256) void k_g1(const float* __restrict__ x,
                                            const float* __restrict__ W1,
                                            float* __restrict__ t1,
                                            __half* __restrict__ t2) {
    __shared__ _Float16 sX[64 * PADW];    // 17.4 KB fp16 x-tile [row][k]
    __shared__ _Float16 sW[DIM * PADW];   // 12.8 KB fp16 W^T [col][k]
    const int t = threadIdx.x;
    const int base = blockIdx.x * 64;
    const int wid = t >> 6, lane = t & 63;

    // stage W^T[col][k] fp16 (once; 24.6 KB source, L2-hot)
    for (int idx = t; idx < DIM * (N_FEAT / 2); idx += 256) {
        int c = idx >> 6;              // 0..47
        int kk = (idx & 63) * 2;       // even k
        __half2 h = __floats2half2_rn(W1[kk * DIM + c], W1[(kk + 1) * DIM + c]);
        *(__half2*)&sX[0];  // no-op guard against DCE reordering (kept trivial)
        *(__half2*)&sW[c * PADW + kk] = h;
    }
    // stage x[row][k] fp16
    #pragma unroll
    for (int i = 0; i < 8; i++) {
        int idx = t + i * 256;
        int row = idx >> 5, kq = idx & 31;
        float4 v = make_float4(0.f, 0.f, 0.f, 0.f);
        if (base + row < N_NODES) v = ((const float4*)x)[(base + row) * 32 + kq];
        *(__half2*)&sX[row * PADW + kq * 4]     = __floats2half2_rn(v.x, v.y);
        *(__half2*)&sX[row * PADW + kq * 4 + 2] = __floats2half2_rn(v.z, v.w);
    }
    __syncthreads();

    const int r16 = wid * 16;          // wave's row stripe
    const int lrow = lane & 15;
    const int lk = (lane >> 4) * 8;

    f32x4 acc1[3], acc2[3];
    #pragma unroll
    for (int c = 0; c < 3; c++) {
        acc1[c] = (f32x4){0.f, 0.f, 0.f, 0.f};
        acc2[c] = (f32x4){0.f, 0.f, 0.f, 0.f};
    }

    #pragma unroll
    for (int ks = 0; ks < 4; ks++) {
        f16x8 a = *(const f16x8*)&sX[(r16 + lrow) * PADW + ks * 32 + lk];
        f16x8 ra;
        #pragma unroll
        for (int j = 0; j < 8; j++)
            ra[j] = a[j] > (_Float16)0 ? a[j] : (_Float16)0;
        #pragma unroll
        for (int c = 0; c < 3; c++) {
            f16x8 b = *(const f16x8*)&sW[(c * 16 + lrow) * PADW + ks * 32 + lk];
            acc1[c] = __builtin_amdgcn_mfma_f32_16x16x32_f16(a,  b, acc1[c], 0, 0, 0);
            acc2[c] = __builtin_amdgcn_mfma_f32_16x16x32_f16(ra, b, acc2[c], 0, 0, 0);
        }
    }

    const int orow = r16 + (lane >> 4) * 4;
    const int ocol = lane & 15;
    #pragma unroll
    for (int q = 0; q < 4; q++) {
        int gr = base + orow + q;
        if (gr < N_NODES) {
            #pragma unroll
            for (int c = 0; c < 3; c++) {
                t1[gr * DIM + c * 16 + ocol] = acc1[c][q];
                t2[gr * DIM + c * 16 + ocol] = __float2half(acc2[c][q]);
            }
        }
    }
}

// ---------------- aggregation: out = relu(tlin + segsum(tmsg_fp16) + bias) ----------------
// 5 nodes per wave: 12 lanes per node, each lane gathers 8B (4 halfs) of the
// 96B message row -> one VMEM instruction serves 5 edges.
// out aliases tlin: read-before-write, same thread, row-exclusive.

__device__ inline float2 h2tof2(unsigned int u) {
    __half2 h = *reinterpret_cast<__half2*>(&u);
    return __half22float2(h);
}

__global__ __launch_bounds__(256) void k_aggr(const float* tlin,
                                              const uint2* __restrict__ tmsg8,  // [N][12] 8B chunks
                                              const int* __restrict__ row_ptr,
                                              const int* __restrict__ ssrc,
                                              const float* __restrict__ bias,
                                              float* out) {
    const int t = threadIdx.x;
    const int wid = t >> 6, lane = t & 63;
    const int sub = lane / 12;          // 0..5 (5 == idle lanes 60-63)
    const int fl  = lane - sub * 12;    // 0..11 -> features fl*4 .. fl*4+3
    int n = blockIdx.x * 20 + wid * 5 + sub;
    const bool act = (sub < 5) && (n < N_NODES);
    int start = 0, end = 0;
    if (act) { start = row_ptr[n]; end = row_ptr[n + 1]; }

    float ax = 0.f, ay = 0.f, az = 0.f, aw = 0.f;
    int e = start;
    for (; e + 8 <= end; e += 8) {
        int s0 = ssrc[e], s1 = ssrc[e + 1], s2 = ssrc[e + 2], s3 = ssrc[e + 3];
        int s4 = ssrc[e + 4], s5 = ssrc[e + 5], s6 = ssrc[e + 6], s7 = ssrc[e + 7];
        uint2 v0 = tmsg8[s0 * 12 + fl];
        uint2 v1 = tmsg8[s1 * 12 + fl];
        uint2 v2 = tmsg8[s2 * 12 + fl];
        uint2 v3 = tmsg8[s3 * 12 + fl];
        uint2 v4 = tmsg8[s4 * 12 + fl];
        uint2 v5 = tmsg8[s5 * 12 + fl];
        uint2 v6 = tmsg8[s6 * 12 + fl];
        uint2 v7 = tmsg8[s7 * 12 + fl];
        float2 f;
        f = h2tof2(v0.x); ax += f.x; ay += f.y;  f = h2tof2(v0.y); az += f.x; aw += f.y;
        f = h2tof2(v1.x); ax += f.x; ay += f.y;  f = h2tof2(v1.y); az += f.x; aw += f.y;
        f = h2tof2(v2.x); ax += f.x; ay += f.y;  f = h2tof2(v2.y); az += f.x; aw += f.y;
        f = h2tof2(v3.x); ax += f.x; ay += f.y;  f = h2tof2(v3.y); az += f.x; aw += f.y;
        f = h2tof2(v4.x); ax += f.x; ay += f.y;  f = h2tof2(v4.y); az += f.x; aw += f.y;
        f = h2tof2(v5.x); ax += f.x; ay += f.y;  f = h2tof2(v5.y); az += f.x; aw += f.y;
        f = h2tof2(v6.x); ax += f.x; ay += f.y;  f = h2tof2(v6.y); az += f.x; aw += f.y;
        f = h2tof2(v7.x); ax += f.x; ay += f.y;  f = h2tof2(v7.y); az += f.x; aw += f.y;
    }
    for (; e < end; e++) {
        int s = ssrc[e];
        uint2 v = tmsg8[s * 12 + fl];
        float2 f;
        f = h2tof2(v.x); ax += f.x; ay += f.y;
        f = h2tof2(v.y); az += f.x; aw += f.y;
    }
    if (act) {
        float4 base = ((const float4*)tlin)[n * 12 + fl];
        float4 bi   = ((const float4*)bias)[fl];
        float4 r;
        r.x = fmaxf(base.x + ax + bi.x, 0.f);
        r.y = fmaxf(base.y + ay + bi.y, 0.f);
        r.z = fmaxf(base.z + az + bi.z, 0.f);
        r.w = fmaxf(base.w + aw + bi.w, 0.f);
        ((float4*)out)[n * 12 + fl] = r;
    }
}

// ---------------- chain1: v=u@c1W2+b2; g1=bn1(relu(v)); t3=g1@c2W1 (fp32); t4=relu(g1)@c2W1 (fp16) ----------------
// t3 aliases u: u fully staged to LDS before first sync; writes after; row-exclusive.

__global__ __launch_bounds__(256) void k_chain1(const float* u,
                                                const float* __restrict__ W2,
                                                const float* __restrict__ b2,
                                                const float* __restrict__ bng,
                                                const float* __restrict__ bnb,
                                                const float* __restrict__ bnm,
                                                const float* __restrict__ bnv,
                                                const float* __restrict__ W1n,
                                                float* t3,
                                                __half* __restrict__ t4) {
    __shared__ float sU[64 * PADD];
    __shared__ float sG[64 * PADD];
    __shared__ float sW2[DIM * PADD];
    __shared__ float sW1[DIM * PADD];
    const int t = threadIdx.x;
    const int base = blockIdx.x * 64;

    for (int idx = t; idx < DIM * DIM; idx += 256) {
        int k = idx / DIM, c = idx - k * DIM;
        sW2[c * PADD + k] = W2[idx];
        sW1[c * PADD + k] = W1n[idx];
    }
    for (int idx = t; idx < 64 * 12; idx += 256) {
        int row = idx / 12, kq = idx - row * 12;
        float4 v = make_float4(0.f, 0.f, 0.f, 0.f);
        if (base + row < N_NODES) v = ((const float4*)u)[(base + row) * 12 + kq];
        *(float4*)&sU[row * PADD + kq * 4] = v;
    }
    __syncthreads();

    const int cg = t & 7, rg = t >> 3;
    const int r0 = rg * 2, c0 = cg * 6;

    {
        float g[2][6];
        #pragma unroll
        for (int r = 0; r < 2; r++)
            #pragma unroll
            for (int c = 0; c < 6; c++) g[r][c] = 0.f;

        #pragma unroll 2
        for (int kq = 0; kq < 12; kq++) {
            float4 x0 = *(const float4*)&sU[(r0 + 0) * PADD + kq * 4];
            float4 x1 = *(const float4*)&sU[(r0 + 1) * PADD + kq * 4];
            #pragma unroll
            for (int c = 0; c < 6; c++) {
                float4 w = *(const float4*)&sW2[(c0 + c) * PADD + kq * 4];
                g[0][c] += x0.x * w.x + x0.y * w.y + x0.z * w.z + x0.w * w.w;
                g[1][c] += x1.x * w.x + x1.y * w.y + x1.z * w.z + x1.w * w.w;
            }
        }
        #pragma unroll
        for (int c = 0; c < 6; c++) {
            float bb = b2[c0 + c];
            float sc = bng[c0 + c] * rsqrtf(bnv[c0 + c] + BN_EPS);
            float sh = bnb[c0 + c] - bnm[c0 + c] * sc;
            #pragma unroll
            for (int r = 0; r < 2; r++) {
                float rl = fmaxf(g[r][c] + bb, 0.f);
                sG[(r0 + r) * PADD + c0 + c] = rl * sc + sh;
            }
        }
    }
    __syncthreads();

    {
        float a3[2][6], a4[2][6];
        #pragma unroll
        for (int r = 0; r < 2; r++)
            #pragma unroll
            for (int c = 0; c < 6; c++) { a3[r][c] = 0.f; a4[r][c] = 0.f; }

        #pragma unroll 2
        for (int kq = 0; kq < 12; kq++) {
            float4 x0 = *(const float4*)&sG[(r0 + 0) * PADD + kq * 4];
            float4 x1 = *(const float4*)&sG[(r0 + 1) * PADD + kq * 4];
            float4 p0 = make_float4(fmaxf(x0.x, 0.f), fmaxf(x0.y, 0.f), fmaxf(x0.z, 0.f), fmaxf(x0.w, 0.f));
            float4 p1 = make_float4(fmaxf(x1.x, 0.f), fmaxf(x1.y, 0.f), fmaxf(x1.z, 0.f), fmaxf(x1.w, 0.f));
            #pragma unroll
            for (int c = 0; c < 6; c++) {
                float4 w = *(const float4*)&sW1[(c0 + c) * PADD + kq * 4];
                a3[0][c] += x0.x * w.x + x0.y * w.y + x0.z * w.z + x0.w * w.w;
                a3[1][c] += x1.x * w.x + x1.y * w.y + x1.z * w.z + x1.w * w.w;
                a4[0][c] += p0.x * w.x + p0.y * w.y + p0.z * w.z + p0.w * w.w;
                a4[1][c] += p1.x * w.x + p1.y * w.y + p1.z * w.z + p1.w * w.w;
            }
        }
        #pragma unroll
        for (int r = 0; r < 2; r++) {
            int gr = base + r0 + r;
            if (gr < N_NODES) {
                #pragma unroll
                for (int c = 0; c < 3; c++) {
                    *(float2*)&t3[gr * DIM + c0 + 2 * c] = make_float2(a3[r][2 * c], a3[r][2 * c + 1]);
                    *(__half2*)&t4[gr * DIM + c0 + 2 * c] =
                        __float22half2_rn(make_float2(a4[r][2 * c], a4[r][2 * c + 1]));
                }
            }
        }
    }
}

// ---------------- chain2: v2=u2@c2W2+b2; g2=bn2(relu); z=relu(g2@fc1+b); out=z@fc2+b ----------------

__global__ __launch_bounds__(256) void k_chain2(const float* __restrict__ u2,
                                                const float* __restrict__ W2,
                                                const float* __restrict__ b2,
                                                const float* __restrict__ bng,
                                                const float* __restrict__ bnb,
                                                const float* __restrict__ bnm,
                                                const float* __restrict__ bnv,
                                                const float* __restrict__ fc1W,
                                                const float* __restrict__ fc1b,
                                                const float* __restrict__ fc2W,
                                                const float* __restrict__ fc2b,
                                                float* __restrict__ out) {
    __shared__ float sA[64 * PADD];
    __shared__ float sB[64 * PADD];
    __shared__ float sWa[DIM * PADD];
    __shared__ float sWb[DIM * PADD];
    __shared__ float sWc[N_CLASS * PADD];
    const int t = threadIdx.x;
    const int base = blockIdx.x * 64;

    for (int idx = t; idx < DIM * DIM; idx += 256) {
        int k = idx / DIM, c = idx - k * DIM;
        sWa[c * PADD + k] = W2[idx];
        sWb[c * PADD + k] = fc1W[idx];
    }
    for (int idx = t; idx < DIM * N_CLASS; idx += 256) {
        int k = idx / N_CLASS, c = idx - k * N_CLASS;
        sWc[c * PADD + k] = fc2W[idx];
    }
    for (int idx = t; idx < 64 * 12; idx += 256) {
        int row = idx / 12, kq = idx - row * 12;
        float4 v = make_float4(0.f, 0.f, 0.f, 0.f);
        if (base + row < N_NODES) v = ((const float4*)u2)[(base + row) * 12 + kq];
        *(float4*)&sA[row * PADD + kq * 4] = v;
    }
    __syncthreads();

    const int cg = t & 7, rg = t >> 3;
    const int r0 = rg * 2, c0 = cg * 6;

    {
        float g[2][6];
        #pragma unroll
        for (int r = 0; r < 2; r++)
            #pragma unroll
            for (int c = 0; c < 6; c++) g[r][c] = 0.f;
        #pragma unroll 2
        for (int kq = 0; kq < 12; kq++) {
            float4 x0 = *(const float4*)&sA[(r0 + 0) * PADD + kq * 4];
            float4 x1 = *(const float4*)&sA[(r0 + 1) * PADD + kq * 4];
            #pragma unroll
            for (int c = 0; c < 6; c++) {
                float4 w = *(const float4*)&sWa[(c0 + c) * PADD + kq * 4];
                g[0][c] += x0.x * w.x + x0.y * w.y + x0.z * w.z + x0.w * w.w;
                g[1][c] += x1.x * w.x + x1.y * w.y + x1.z * w.z + x1.w * w.w;
            }
        }
        #pragma unroll
        for (int c = 0; c < 6; c++) {
            float bb = b2[c0 + c];
            float sc = bng[c0 + c] * rsqrtf(bnv[c0 + c] + BN_EPS);
            float sh = bnb[c0 + c] - bnm[c0 + c] * sc;
            #pragma unroll
            for (int r = 0; r < 2; r++) {
                float rl = fmaxf(g[r][c] + bb, 0.f);
                sB[(r0 + r) * PADD + c0 + c] = rl * sc + sh;
            }
        }
    }
    __syncthreads();

    {
        float z[2][6];
        #pragma unroll
        for (int r = 0; r < 2; r++)
            #pragma unroll
            for (int c = 0; c < 6; c++) z[r][c] = 0.f;
        #pragma unroll 2
        for (int kq = 0; kq < 12; kq++) {
            float4 x0 = *(const float4*)&sB[(r0 + 0) * PADD + kq * 4];
            float4 x1 = *(const float4*)&sB[(r0 + 1) * PADD + kq * 4];
            #pragma unroll
            for (int c = 0; c < 6; c++) {
                float4 w = *(const float4*)&sWb[(c0 + c) * PADD + kq * 4];
                z[0][c] += x0.x * w.x + x0.y * w.y + x0.z * w.z + x0.w * w.w;
                z[1][c] += x1.x * w.x + x1.y * w.y + x1.z * w.z + x1.w * w.w;
            }
        }
        __syncthreads();
        #pragma unroll
        for (int c = 0; c < 6; c++) {
            float bb = fc1b[c0 + c];
            #pragma unroll
            for (int r = 0; r < 2; r++)
                sA[(r0 + r) * PADD + c0 + c] = fmaxf(z[r][c] + bb, 0.f);
        }
    }
    __syncthreads();

    if (cg < 6) {
        const int cc0 = cg * 3;
        float o[2][3];
        #pragma unroll
        for (int r = 0; r < 2; r++)
            #pragma unroll
            for (int c = 0; c < 3; c++) o[r][c] = 0.f;
        #pragma unroll 2
        for (int kq = 0; kq < 12; kq++) {
            float4 x0 = *(const float4*)&sA[(r0 + 0) * PADD + kq * 4];
            float4 x1 = *(const float4*)&sA[(r0 + 1) * PADD + kq * 4];
            #pragma unroll
            for (int c = 0; c < 3; c++) {
                float4 w = *(const float4*)&sWc[(cc0 + c) * PADD + kq * 4];
                o[0][c] += x0.x * w.x + x0.y * w.y + x0.z * w.z + x0.w * w.w;
                o[1][c] += x1.x * w.x + x1.y * w.y + x1.z * w.z + x1.w * w.w;
            }
        }
        #pragma unroll
        for (int r = 0; r < 2; r++) {
            int gr = base + r0 + r;
            if (gr < N_NODES) {
                #pragma unroll
                for (int c = 0; c < 3; c++)
                    out[gr * N_CLASS + cc0 + c] = o[r][c] + fc2b[cc0 + c];
            }
        }
    }
}

// ---------------- launch ----------------

extern "C" void kernel_launch(void* const* d_in, const int* in_sizes, int n_in,
                              void* d_out, int out_size, void* d_ws, size_t ws_size,
                              hipStream_t stream) {
    const float* x     = (const float*)d_in[0];
    const int*   ei    = (const int*)d_in[1];
    const float* c1_W1 = (const float*)d_in[2];
    const float* c1_b1 = (const float*)d_in[3];
    const float* c1_W2 = (const float*)d_in[4];
    const float* c1_b2 = (const float*)d_in[5];
    const float* c2_W1 = (const float*)d_in[6];
    const float* c2_b1 = (const float*)d_in[7];
    const float* c2_W2 = (const float*)d_in[8];
    const float* c2_b2 = (const float*)d_in[9];
    const float* bn1_g = (const float*)d_in[10];
    const float* bn1_b = (const float*)d_in[11];
    const float* bn1_m = (const float*)d_in[12];
    const float* bn1_v = (const float*)d_in[13];
    const float* bn2_g = (const float*)d_in[14];
    const float* bn2_b = (const float*)d_in[15];
    const float* bn2_m = (const float*)d_in[16];
    const float* bn2_v = (const float*)d_in[17];
    const float* fc1_W = (const float*)d_in[18];
    const float* fc1_b = (const float*)d_in[19];
    const float* fc2_W = (const float*)d_in[20];
    const float* fc2_b = (const float*)d_in[21];
    float* out = (float*)d_out;

    char* ws = (char*)d_ws;
    size_t o = 0;
    auto take = [&](size_t bytes) {
        void* p = ws + o;
        o = (o + bytes + 255) & ~(size_t)255;
        return p;
    };
    unsigned int* pairs = (unsigned int*)take((size_t)N_EDGES * 4);   // 12.8 MB (packed)
    int*  sorted_src    = (int*)take((size_t)N_EDGES * 4);            // 12.8 MB
    int*  row_ptr       = (int*)take((size_t)(N_NODES + 1) * 4);
    int*  bcnt          = (int*)take((size_t)NBUCK * 4);
    int*  bptr          = (int*)take((size_t)(NBUCK + 1) * 4);
    int*  bcursor       = (int*)take((size_t)NBUCK * 4);
    float*  t1          = (float*)take((size_t)N_NODES * DIM * 4);    // aliased: t1/u/t3/u2 (fp32)
    __half* t2h         = (__half*)take((size_t)N_NODES * DIM * 2);   // t2/t4 (fp16 messages)
    (void)ws_size; (void)in_sizes; (void)n_in; (void)out_size;

    const int NB64 = (N_NODES + 63) / 64;    // 1563
    const int NB20 = (N_NODES + 19) / 20;    // 5000

    hipMemsetAsync(bcnt, 0, (size_t)NBUCK * 4, stream);
    k_bhist<<<NBLK_E, 256, 0, stream>>>(ei, bcnt);
    k_bscan<<<1, 1024, 0, stream>>>(bcnt, bptr, bcursor);
    k_bin<<<NBLK_E, 256, 0, stream>>>(ei, bcursor, pairs);
    k_sort<<<NBUCK, 256, 0, stream>>>(pairs, bptr, row_ptr, sorted_src);

    k_g1<<<NB64, 256, 0, stream>>>(x, c1_W1, t1, t2h);
    k_aggr<<<NB20, 256, 0, stream>>>(t1, (const uint2*)t2h, row_ptr, sorted_src, c1_b1, t1);
    k_chain1<<<NB64, 256, 0, stream>>>(t1, c1_W2, c1_b2, bn1_g, bn1_b, bn1_m, bn1_v,
                                       c2_W1, t1, t2h);
    k_aggr<<<NB20, 256, 0, stream>>>(t1, (const uint2*)t2h, row_ptr, sorted_src, c2_b1, t1);
    k_chain2<<<NB64, 256, 0, stream>>>(t1, c2_W2, c2_b2, bn2_g, bn2_b, bn2_m, bn2_v,
                                       fc1_W, fc1_b, fc2_W, fc2_b, out);
}

// Round 11
// 285.075 us; speedup vs baseline: 1.2441x; 1.1541x over previous
//
#include <hip/hip_runtime.h>
#include <hip/hip_fp16.h>

#define N_NODES 100000
#define N_EDGES 3200000
#define N_FEAT  128
#define DIM     48
#define N_CLASS 18
#define BN_EPS  1e-5f

#define PADW 136   // f16 MFMA K=128 tile row stride (272 B): 2-way bank alias (free)
#define PADC 72    // f16 MFMA K=64 tile row stride (144 B): 2-way bank alias (free)
#define MROW 64    // padded message-row stride in halfs (128 B = 1 cache line)

#define BSH    7                                   // bucket = dst >> 7 (128 nodes)
#define BROWS  128                                 // nodes per bucket
#define NBUCK  ((N_NODES + BROWS - 1) / BROWS)     // 782
#define EPB    4096                                // edges per binning block
#define NBLK_E ((N_EDGES + EPB - 1) / EPB)         // 782

typedef __attribute__((ext_vector_type(8))) _Float16 f16x8;
typedef __attribute__((ext_vector_type(4))) float f32x4;

// packed edge: (src << 7) | (dst & 127).  src < 2^17, fits 24 bits.

// ---------------- bucket-granular edge preprocessing ----------------

__global__ __launch_bounds__(256) void k_bhist(const int* __restrict__ ei,
                                               int* __restrict__ bcnt) {
    __shared__ int h[NBUCK];
    const int t = threadIdx.x;
    for (int i = t; i < NBUCK; i += 256) h[i] = 0;
    __syncthreads();
    int bs = blockIdx.x * EPB;
    int ce = min(EPB, N_EDGES - bs);
    for (int i = t; i < ce; i += 256) {
        int d = ei[N_EDGES + bs + i];
        atomicAdd(&h[d >> BSH], 1);
    }
    __syncthreads();
    for (int i = t; i < NBUCK; i += 256)
        if (h[i]) atomicAdd(&bcnt[i], h[i]);
}

__global__ __launch_bounds__(1024) void k_bscan(const int* __restrict__ bcnt,
                                                int* __restrict__ bptr,
                                                int* __restrict__ bcursor) {
    __shared__ int s[1024];
    const int t = threadIdx.x;
    int v = (t < NBUCK) ? bcnt[t] : 0;
    s[t] = v;
    __syncthreads();
    for (int off = 1; off < 1024; off <<= 1) {
        int u = (t >= off) ? s[t - off] : 0;
        __syncthreads();
        s[t] += u;
        __syncthreads();
    }
    if (t < NBUCK) {
        int excl = s[t] - v;
        bptr[t] = excl;
        bcursor[t] = excl;
        if (t == NBUCK - 1) bptr[NBUCK] = s[t];
    }
}

__global__ __launch_bounds__(256) void k_bin(const int* __restrict__ ei,
                                             int* __restrict__ bcursor,
                                             unsigned int* __restrict__ pairs) {
    __shared__ int h[NBUCK];
    __shared__ int pos[NBUCK];
    __shared__ int partial[256];
    __shared__ int2 stg[EPB];
    const int t = threadIdx.x;
    const int bs = blockIdx.x * EPB;
    const int ce = min(EPB, N_EDGES - bs);

    int sv[16], dv[16];
    #pragma unroll
    for (int i = 0; i < 16; i++) {
        int e = t + i * 256;
        if (e < ce) { sv[i] = ei[bs + e]; dv[i] = ei[N_EDGES + bs + e]; }
        else { sv[i] = 0; dv[i] = -1; }
    }
    for (int i = t; i < NBUCK; i += 256) h[i] = 0;
    __syncthreads();
    #pragma unroll
    for (int i = 0; i < 16; i++)
        if (dv[i] >= 0) atomicAdd(&h[dv[i] >> BSH], 1);
    __syncthreads();

    const int c0 = t * 4;
    int l0 = 0, l1 = 0, l2 = 0, l3 = 0, sum = 0;
    if (c0 < NBUCK) {
        l0 = h[c0]; sum = l0;
        if (c0 + 1 < NBUCK) { l1 = h[c0 + 1]; sum += l1; }
        if (c0 + 2 < NBUCK) { l2 = h[c0 + 2]; sum += l2; }
        if (c0 + 3 < NBUCK) { l3 = h[c0 + 3]; sum += l3; }
    }
    partial[t] = sum;
    __syncthreads();
    for (int off = 1; off < 256; off <<= 1) {
        int u = (t >= off) ? partial[t - off] : 0;
        __syncthreads();
        partial[t] += u;
        __syncthreads();
    }
    int run = partial[t] - sum;
    if (c0 < NBUCK) {
        pos[c0] = run; run += l0;
        if (c0 + 1 < NBUCK) { pos[c0 + 1] = run; run += l1; }
        if (c0 + 2 < NBUCK) { pos[c0 + 2] = run; run += l2; }
        if (c0 + 3 < NBUCK) { pos[c0 + 3] = run; run += l3; }
    }
    __syncthreads();

    for (int b = t; b < NBUCK; b += 256) {
        int cnt = h[b];
        if (cnt > 0) {
            int g = atomicAdd(&bcursor[b], cnt);
            h[b] = g - pos[b];
        }
    }
    __syncthreads();

    #pragma unroll
    for (int i = 0; i < 16; i++) {
        if (dv[i] >= 0) {
            int b = dv[i] >> BSH;
            int p = atomicAdd(&pos[b], 1);
            stg[p] = make_int2(sv[i], dv[i]);
        }
    }
    __syncthreads();

    for (int j = t; j < ce; j += 256) {
        int2 pr = stg[j];
        pairs[j + h[pr.y >> BSH]] =
            ((unsigned int)pr.x << 7) | (unsigned int)(pr.y & (BROWS - 1));
    }
}

__global__ __launch_bounds__(256) void k_sort(const unsigned int* __restrict__ pairs,
                                              const int* __restrict__ bptr,
                                              int* __restrict__ row_ptr,
                                              int* __restrict__ sorted_src) {
    __shared__ int hist[BROWS];
    __shared__ int pos[BROWS];
    const int t = threadIdx.x;
    const int b = blockIdx.x;
    const int nbase = b << BSH;
    const int start = bptr[b], end = bptr[b + 1];

    if (t < BROWS) hist[t] = 0;
    __syncthreads();
    for (int e = start + t; e < end; e += 256) {
        atomicAdd(&hist[pairs[e] & (BROWS - 1)], 1);
    }
    __syncthreads();
    if (t < BROWS) pos[t] = hist[t];
    __syncthreads();
    for (int off = 1; off < BROWS; off <<= 1) {
        int v = 0;
        if (t < BROWS && t >= off) v = pos[t - off];
        __syncthreads();
        if (t < BROWS) pos[t] += v;
        __syncthreads();
    }
    if (t < BROWS) {
        int rp = start + pos[t] - hist[t];
        int n = nbase + t;
        if (n < N_NODES) row_ptr[n] = rp;
        pos[t] = rp;
    }
    if (b == 0 && t == 0) row_ptr[N_NODES] = N_EDGES;
    __syncthreads();
    for (int e = start + t; e < end; e += 256) {
        unsigned int p = pairs[e];
        int idx = atomicAdd(&pos[p & (BROWS - 1)], 1);
        sorted_src[idx] = (int)(p >> 7);
    }
}

// ---------------- conv1 front (MFMA): t1 = x@W1 (fp32), t2 = relu(x)@W1 (fp16, 128B rows) ----------------

__global__ __launch_bounds__(256) void k_g1(const float* __restrict__ x,
                                            const float* __restrict__ W1,
                                            float* __restrict__ t1,
                                            __half* __restrict__ t2) {
    __shared__ _Float16 sX[64 * PADW];    // 17.4 KB fp16 x-tile [row][k]
    __shared__ _Float16 sW[DIM * PADW];   // 13.1 KB fp16 W^T [col][k]
    const int t = threadIdx.x;
    const int base = blockIdx.x * 64;
    const int wid = t >> 6, lane = t & 63;

    for (int idx = t; idx < DIM * (N_FEAT / 2); idx += 256) {
        int c = idx >> 6;
        int kk = (idx & 63) * 2;
        *(__half2*)&sW[c * PADW + kk] =
            __floats2half2_rn(W1[kk * DIM + c], W1[(kk + 1) * DIM + c]);
    }
    #pragma unroll
    for (int i = 0; i < 8; i++) {
        int idx = t + i * 256;
        int row = idx >> 5, kq = idx & 31;
        float4 v = make_float4(0.f, 0.f, 0.f, 0.f);
        if (base + row < N_NODES) v = ((const float4*)x)[(base + row) * 32 + kq];
        *(__half2*)&sX[row * PADW + kq * 4]     = __floats2half2_rn(v.x, v.y);
        *(__half2*)&sX[row * PADW + kq * 4 + 2] = __floats2half2_rn(v.z, v.w);
    }
    __syncthreads();

    const int r16 = wid * 16;
    const int lrow = lane & 15;
    const int lk = (lane >> 4) * 8;

    f32x4 acc1[3], acc2[3];
    #pragma unroll
    for (int c = 0; c < 3; c++) {
        acc1[c] = (f32x4){0.f, 0.f, 0.f, 0.f};
        acc2[c] = (f32x4){0.f, 0.f, 0.f, 0.f};
    }

    #pragma unroll
    for (int ks = 0; ks < 4; ks++) {
        f16x8 a = *(const f16x8*)&sX[(r16 + lrow) * PADW + ks * 32 + lk];
        f16x8 ra;
        #pragma unroll
        for (int j = 0; j < 8; j++)
            ra[j] = a[j] > (_Float16)0 ? a[j] : (_Float16)0;
        #pragma unroll
        for (int c = 0; c < 3; c++) {
            f16x8 b = *(const f16x8*)&sW[(c * 16 + lrow) * PADW + ks * 32 + lk];
            acc1[c] = __builtin_amdgcn_mfma_f32_16x16x32_f16(a,  b, acc1[c], 0, 0, 0);
            acc2[c] = __builtin_amdgcn_mfma_f32_16x16x32_f16(ra, b, acc2[c], 0, 0, 0);
        }
    }

    const int orow = r16 + (lane >> 4) * 4;
    const int ocol = lane & 15;
    #pragma unroll
    for (int q = 0; q < 4; q++) {
        int gr = base + orow + q;
        if (gr < N_NODES) {
            #pragma unroll
            for (int c = 0; c < 3; c++) {
                t1[gr * DIM + c * 16 + ocol] = acc1[c][q];
                t2[gr * MROW + c * 16 + ocol] = __float2half(acc2[c][q]);
            }
        }
    }
}

// ---------------- aggregation: out = relu(tlin + segsum(tmsg_fp16) + bias) ----------------
// 5 nodes/wave, 12 lanes/node, 8B/lane; message rows padded to 128B (1 line/row).
// out aliases tlin: read-before-write, same thread, row-exclusive.

__device__ inline float2 h2tof2(unsigned int u) {
    __half2 h = *reinterpret_cast<__half2*>(&u);
    return __half22float2(h);
}

__global__ __launch_bounds__(256) void k_aggr(const float* tlin,
                                              const uint2* __restrict__ tmsg8,  // [N][16] 8B chunks
                                              const int* __restrict__ row_ptr,
                                              const int* __restrict__ ssrc,
                                              const float* __restrict__ bias,
                                              float* out) {
    const int t = threadIdx.x;
    const int wid = t >> 6, lane = t & 63;
    const int sub = lane / 12;
    const int fl  = lane - sub * 12;
    int n = blockIdx.x * 20 + wid * 5 + sub;
    const bool act = (sub < 5) && (n < N_NODES);
    int start = 0, end = 0;
    if (act) { start = row_ptr[n]; end = row_ptr[n + 1]; }

    float ax = 0.f, ay = 0.f, az = 0.f, aw = 0.f;
    int e = start;
    for (; e + 8 <= end; e += 8) {
        int s0 = ssrc[e], s1 = ssrc[e + 1], s2 = ssrc[e + 2], s3 = ssrc[e + 3];
        int s4 = ssrc[e + 4], s5 = ssrc[e + 5], s6 = ssrc[e + 6], s7 = ssrc[e + 7];
        uint2 v0 = tmsg8[s0 * 16 + fl];
        uint2 v1 = tmsg8[s1 * 16 + fl];
        uint2 v2 = tmsg8[s2 * 16 + fl];
        uint2 v3 = tmsg8[s3 * 16 + fl];
        uint2 v4 = tmsg8[s4 * 16 + fl];
        uint2 v5 = tmsg8[s5 * 16 + fl];
        uint2 v6 = tmsg8[s6 * 16 + fl];
        uint2 v7 = tmsg8[s7 * 16 + fl];
        float2 f;
        f = h2tof2(v0.x); ax += f.x; ay += f.y;  f = h2tof2(v0.y); az += f.x; aw += f.y;
        f = h2tof2(v1.x); ax += f.x; ay += f.y;  f = h2tof2(v1.y); az += f.x; aw += f.y;
        f = h2tof2(v2.x); ax += f.x; ay += f.y;  f = h2tof2(v2.y); az += f.x; aw += f.y;
        f = h2tof2(v3.x); ax += f.x; ay += f.y;  f = h2tof2(v3.y); az += f.x; aw += f.y;
        f = h2tof2(v4.x); ax += f.x; ay += f.y;  f = h2tof2(v4.y); az += f.x; aw += f.y;
        f = h2tof2(v5.x); ax += f.x; ay += f.y;  f = h2tof2(v5.y); az += f.x; aw += f.y;
        f = h2tof2(v6.x); ax += f.x; ay += f.y;  f = h2tof2(v6.y); az += f.x; aw += f.y;
        f = h2tof2(v7.x); ax += f.x; ay += f.y;  f = h2tof2(v7.y); az += f.x; aw += f.y;
    }
    for (; e < end; e++) {
        int s = ssrc[e];
        uint2 v = tmsg8[s * 16 + fl];
        float2 f;
        f = h2tof2(v.x); ax += f.x; ay += f.y;
        f = h2tof2(v.y); az += f.x; aw += f.y;
    }
    if (act) {
        float4 base = ((const float4*)tlin)[n * 12 + fl];
        float4 bi   = ((const float4*)bias)[fl];
        float4 r;
        r.x = fmaxf(base.x + ax + bi.x, 0.f);
        r.y = fmaxf(base.y + ay + bi.y, 0.f);
        r.z = fmaxf(base.z + az + bi.z, 0.f);
        r.w = fmaxf(base.w + aw + bi.w, 0.f);
        ((float4*)out)[n * 12 + fl] = r;
    }
}

// ---------------- chain1 (MFMA): v=u@c1W2+b2; g=bn1(relu(v)); t3=g@c2W1 (fp32); t4=relu(g)@c2W1 (fp16, 128B rows) ----------------
// K=48 zero-padded to 64. t3 aliases u (u staged before first sync; writes after; row-exclusive).

__global__ __launch_bounds__(256) void k_chain1(const float* u,
                                                const float* __restrict__ W2,
                                                const float* __restrict__ b2,
                                                const float* __restrict__ bng,
                                                const float* __restrict__ bnb,
                                                const float* __restrict__ bnm,
                                                const float* __restrict__ bnv,
                                                const float* __restrict__ W1n,
                                                float* t3,
                                                __half* __restrict__ t4) {
    __shared__ _Float16 sU[64 * PADC];
    __shared__ _Float16 sG[64 * PADC];
    __shared__ _Float16 sW2t[DIM * PADC];
    __shared__ _Float16 sW1t[DIM * PADC];
    __shared__ float sb2[DIM], ssc[DIM], ssh[DIM];
    const int t = threadIdx.x;
    const int base = blockIdx.x * 64;
    const int wid = t >> 6, lane = t & 63;

    if (t < DIM) {
        sb2[t] = b2[t];
        float sc = bng[t] * rsqrtf(bnv[t] + BN_EPS);
        ssc[t] = sc;
        ssh[t] = bnb[t] - bnm[t] * sc;
    }
    // stage W^T fp16 (valid k<48)
    for (int idx = t; idx < DIM * 24; idx += 256) {
        int c = idx / 24, kk = (idx - c * 24) * 2;
        sW2t[c * PADC + kk]     = (_Float16)W2[kk * DIM + c];
        sW2t[c * PADC + kk + 1] = (_Float16)W2[(kk + 1) * DIM + c];
        sW1t[c * PADC + kk]     = (_Float16)W1n[kk * DIM + c];
        sW1t[c * PADC + kk + 1] = (_Float16)W1n[(kk + 1) * DIM + c];
    }
    // zero-pad k 48..63
    for (int idx = t; idx < DIM * 16; idx += 256) {
        int c = idx >> 4, j = idx & 15;
        sW2t[c * PADC + 48 + j] = (_Float16)0;
        sW1t[c * PADC + 48 + j] = (_Float16)0;
    }
    for (int idx = t; idx < 64 * 16; idx += 256) {
        int r = idx >> 4, j = idx & 15;
        sU[r * PADC + 48 + j] = (_Float16)0;
        sG[r * PADC + 48 + j] = (_Float16)0;
    }
    // stage u fp16
    for (int idx = t; idx < 64 * 24; idx += 256) {
        int row = idx / 24, kk = (idx - row * 24) * 2;
        float2 v = make_float2(0.f, 0.f);
        if (base + row < N_NODES) v = *(const float2*)&u[(base + row) * DIM + kk];
        sU[row * PADC + kk]     = (_Float16)v.x;
        sU[row * PADC + kk + 1] = (_Float16)v.y;
    }
    __syncthreads();

    const int r16 = wid * 16;
    const int lrow = lane & 15;
    const int lk = (lane >> 4) * 8;
    const int orow = r16 + (lane >> 4) * 4;
    const int ocol = lane & 15;

    // GEMM1: v = u@W2
    f32x4 av[3];
    #pragma unroll
    for (int c = 0; c < 3; c++) av[c] = (f32x4){0.f, 0.f, 0.f, 0.f};
    #pragma unroll
    for (int ks = 0; ks < 2; ks++) {
        f16x8 a = *(const f16x8*)&sU[(r16 + lrow) * PADC + ks * 32 + lk];
        #pragma unroll
        for (int c = 0; c < 3; c++) {
            f16x8 b = *(const f16x8*)&sW2t[(c * 16 + lrow) * PADC + ks * 32 + lk];
            av[c] = __builtin_amdgcn_mfma_f32_16x16x32_f16(a, b, av[c], 0, 0, 0);
        }
    }
    // epilogue: g = bn1(relu(v + b2)) -> sG (fp16)
    #pragma unroll
    for (int c = 0; c < 3; c++) {
        int col = c * 16 + ocol;
        float bb = sb2[col], sc = ssc[col], sh = ssh[col];
        #pragma unroll
        for (int q = 0; q < 4; q++) {
            float rl = fmaxf(av[c][q] + bb, 0.f);
            sG[(orow + q) * PADC + col] = (_Float16)(rl * sc + sh);
        }
    }
    __syncthreads();

    // GEMM2 (dual): t3 = g@W1n, t4 = relu(g)@W1n
    f32x4 a3[3], a4[3];
    #pragma unroll
    for (int c = 0; c < 3; c++) {
        a3[c] = (f32x4){0.f, 0.f, 0.f, 0.f};
        a4[c] = (f32x4){0.f, 0.f, 0.f, 0.f};
    }
    #pragma unroll
    for (int ks = 0; ks < 2; ks++) {
        f16x8 a = *(const f16x8*)&sG[(r16 + lrow) * PADC + ks * 32 + lk];
        f16x8 ra;
        #pragma unroll
        for (int j = 0; j < 8; j++)
            ra[j] = a[j] > (_Float16)0 ? a[j] : (_Float16)0;
        #pragma unroll
        for (int c = 0; c < 3; c++) {
            f16x8 b = *(const f16x8*)&sW1t[(c * 16 + lrow) * PADC + ks * 32 + lk];
            a3[c] = __builtin_amdgcn_mfma_f32_16x16x32_f16(a,  b, a3[c], 0, 0, 0);
            a4[c] = __builtin_amdgcn_mfma_f32_16x16x32_f16(ra, b, a4[c], 0, 0, 0);
        }
    }
    #pragma unroll
    for (int q = 0; q < 4; q++) {
        int gr = base + orow + q;
        if (gr < N_NODES) {
            #pragma unroll
            for (int c = 0; c < 3; c++) {
                t3[gr * DIM + c * 16 + ocol] = a3[c][q];
                t4[gr * MROW + c * 16 + ocol] = __float2half(a4[c][q]);
            }
        }
    }
}

// ---------------- chain2 (MFMA): v2=u2@c2W2+b2; g2=bn2(relu); z=relu(g2@fc1+b); out=z@fc2+b ----------------

__global__ __launch_bounds__(256) void k_chain2(const float* __restrict__ u2,
                                                const float* __restrict__ W2,
                                                const float* __restrict__ b2,
                                                const float* __restrict__ bng,
                                                const float* __restrict__ bnb,
                                                const float* __restrict__ bnm,
                                                const float* __restrict__ bnv,
                                                const float* __restrict__ fc1W,
                                                const float* __restrict__ fc1b,
                                                const float* __restrict__ fc2W,
                                                const float* __restrict__ fc2b,
                                                float* __restrict__ out) {
    __shared__ _Float16 sA[64 * PADC];     // u2, later z
    __shared__ _Float16 sG[64 * PADC];     // g2
    __shared__ _Float16 sWa[DIM * PADC];   // c2W2^T
    __shared__ _Float16 sWb[DIM * PADC];   // fc1W^T
    __shared__ _Float16 sWc[32 * PADC];    // fc2W^T (cols 0..17 valid)
    __shared__ float sb2[DIM], ssc[DIM], ssh[DIM], sfb1[DIM], sfb2[N_CLASS];
    const int t = threadIdx.x;
    const int base = blockIdx.x * 64;
    const int wid = t >> 6, lane = t & 63;

    if (t < DIM) {
        sb2[t] = b2[t];
        float sc = bng[t] * rsqrtf(bnv[t] + BN_EPS);
        ssc[t] = sc;
        ssh[t] = bnb[t] - bnm[t] * sc;
        sfb1[t] = fc1b[t];
    }
    if (t >= 64 && t < 64 + N_CLASS) sfb2[t - 64] = fc2b[t - 64];

    for (int idx = t; idx < DIM * 24; idx += 256) {
        int c = idx / 24, kk = (idx - c * 24) * 2;
        sWa[c * PADC + kk]     = (_Float16)W2[kk * DIM + c];
        sWa[c * PADC + kk + 1] = (_Float16)W2[(kk + 1) * DIM + c];
        sWb[c * PADC + kk]     = (_Float16)fc1W[kk * DIM + c];
        sWb[c * PADC + kk + 1] = (_Float16)fc1W[(kk + 1) * DIM + c];
    }
    for (int idx = t; idx < DIM * 16; idx += 256) {
        int c = idx >> 4, j = idx & 15;
        sWa[c * PADC + 48 + j] = (_Float16)0;
        sWb[c * PADC + 48 + j] = (_Float16)0;
    }
    // fc2W^T: valid col<18, k<48; zero col 18..31 (all k<64) and k 48..63 (all cols)
    for (int idx = t; idx < N_CLASS * DIM; idx += 256) {
        int c = idx / DIM, k = idx - c * DIM;
        sWc[c * PADC + k] = (_Float16)fc2W[k * N_CLASS + c];
    }
    for (int idx = t; idx < 32 * 16; idx += 256) {
        int c = idx >> 4, j = idx & 15;
        sWc[c * PADC + 48 + j] = (_Float16)0;
    }
    for (int idx = t; idx < 14 * 48; idx += 256) {
        int c = 18 + idx / 48, k = idx - (idx / 48) * 48;
        sWc[c * PADC + k] = (_Float16)0;
    }
    for (int idx = t; idx < 64 * 16; idx += 256) {
        int r = idx >> 4, j = idx & 15;
        sA[r * PADC + 48 + j] = (_Float16)0;
        sG[r * PADC + 48 + j] = (_Float16)0;
    }
    for (int idx = t; idx < 64 * 24; idx += 256) {
        int row = idx / 24, kk = (idx - row * 24) * 2;
        float2 v = make_float2(0.f, 0.f);
        if (base + row < N_NODES) v = *(const float2*)&u2[(base + row) * DIM + kk];
        sA[row * PADC + kk]     = (_Float16)v.x;
        sA[row * PADC + kk + 1] = (_Float16)v.y;
    }
    __syncthreads();

    const int r16 = wid * 16;
    const int lrow = lane & 15;
    const int lk = (lane >> 4) * 8;
    const int orow = r16 + (lane >> 4) * 4;
    const int ocol = lane & 15;

    // GEMM1: v2 = u2@W2 -> g2 = bn2(relu(v2+b2)) -> sG
    {
        f32x4 av[3];
        #pragma unroll
        for (int c = 0; c < 3; c++) av[c] = (f32x4){0.f, 0.f, 0.f, 0.f};
        #pragma unroll
        for (int ks = 0; ks < 2; ks++) {
            f16x8 a = *(const f16x8*)&sA[(r16 + lrow) * PADC + ks * 32 + lk];
            #pragma unroll
            for (int c = 0; c < 3; c++) {
                f16x8 b = *(const f16x8*)&sWa[(c * 16 + lrow) * PADC + ks * 32 + lk];
                av[c] = __builtin_amdgcn_mfma_f32_16x16x32_f16(a, b, av[c], 0, 0, 0);
            }
        }
        #pragma unroll
        for (int c = 0; c < 3; c++) {
            int col = c * 16 + ocol;
            float bb = sb2[col], sc = ssc[col], sh = ssh[col];
            #pragma unroll
            for (int q = 0; q < 4; q++) {
                float rl = fmaxf(av[c][q] + bb, 0.f);
                sG[(orow + q) * PADC + col] = (_Float16)(rl * sc + sh);
            }
        }
    }
    __syncthreads();

    // GEMM2: z = relu(g2@fc1 + b1) -> sA (overwrite; all GEMM1 reads of sA done)
    {
        f32x4 az[3];
        #pragma unroll
        for (int c = 0; c < 3; c++) az[c] = (f32x4){0.f, 0.f, 0.f, 0.f};
        #pragma unroll
        for (int ks = 0; ks < 2; ks++) {
            f16x8 a = *(const f16x8*)&sG[(r16 + lrow) * PADC + ks * 32 + lk];
            #pragma unroll
            for (int c = 0; c < 3; c++) {
                f16x8 b = *(const f16x8*)&sWb[(c * 16 + lrow) * PADC + ks * 32 + lk];
                az[c] = __builtin_amdgcn_mfma_f32_16x16x32_f16(a, b, az[c], 0, 0, 0);
            }
        }
        __syncthreads();   // all sA reads (GEMM1) and sG reads complete before z overwrite
        #pragma unroll
        for (int c = 0; c < 3; c++) {
            int col = c * 16 + ocol;
            float bb = sfb1[col];
            #pragma unroll
            for (int q = 0; q < 4; q++)
                sA[(orow + q) * PADC + col] = (_Float16)fmaxf(az[c][q] + bb, 0.f);
        }
    }
    __syncthreads();

    // GEMM3: out = z@fc2 + b  (N=18: col-blocks 0..15, 16..31 w/ zero cols)
    {
        f32x4 ao[2];
        #pragma unroll
        for (int c = 0; c < 2; c++) ao[c] = (f32x4){0.f, 0.f, 0.f, 0.f};
        #pragma unroll
        for (int ks = 0; ks < 2; ks++) {
            f16x8 a = *(const f16x8*)&sA[(r16 + lrow) * PADC + ks * 32 + lk];
            #pragma unroll
            for (int c = 0; c < 2; c++) {
                f16x8 b = *(const f16x8*)&sWc[(c * 16 + lrow) * PADC + ks * 32 + lk];
                ao[c] = __builtin_amdgcn_mfma_f32_16x16x32_f16(a, b, ao[c], 0, 0, 0);
            }
        }
        #pragma unroll
        for (int q = 0; q < 4; q++) {
            int gr = base + orow + q;
            if (gr < N_NODES) {
                #pragma unroll
                for (int c = 0; c < 2; c++) {
                    int col = c * 16 + ocol;
                    if (col < N_CLASS)
                        out[gr * N_CLASS + col] = ao[c][q] + sfb2[col];
                }
            }
        }
    }
}

// ---------------- launch ----------------

extern "C" void kernel_launch(void* const* d_in, const int* in_sizes, int n_in,
                              void* d_out, int out_size, void* d_ws, size_t ws_size,
                              hipStream_t stream) {
    const float* x     = (const float*)d_in[0];
    const int*   ei    = (const int*)d_in[1];
    const float* c1_W1 = (const float*)d_in[2];
    const float* c1_b1 = (const float*)d_in[3];
    const float* c1_W2 = (const float*)d_in[4];
    const float* c1_b2 = (const float*)d_in[5];
    const float* c2_W1 = (const float*)d_in[6];
    const float* c2_b1 = (const float*)d_in[7];
    const float* c2_W2 = (const float*)d_in[8];
    const float* c2_b2 = (const float*)d_in[9];
    const float* bn1_g = (const float*)d_in[10];
    const float* bn1_b = (const float*)d_in[11];
    const float* bn1_m = (const float*)d_in[12];
    const float* bn1_v = (const float*)d_in[13];
    const float* bn2_g = (const float*)d_in[14];
    const float* bn2_b = (const float*)d_in[15];
    const float* bn2_m = (const float*)d_in[16];
    const float* bn2_v = (const float*)d_in[17];
    const float* fc1_W = (const float*)d_in[18];
    const float* fc1_b = (const float*)d_in[19];
    const float* fc2_W = (const float*)d_in[20];
    const float* fc2_b = (const float*)d_in[21];
    float* out = (float*)d_out;

    char* ws = (char*)d_ws;
    size_t o = 0;
    auto take = [&](size_t bytes) {
        void* p = ws + o;
        o = (o + bytes + 255) & ~(size_t)255;
        return p;
    };
    unsigned int* pairs = (unsigned int*)take((size_t)N_EDGES * 4);    // 12.8 MB (packed)
    int*  sorted_src    = (int*)take((size_t)N_EDGES * 4);             // 12.8 MB
    int*  row_ptr       = (int*)take((size_t)(N_NODES + 1) * 4);
    int*  bcnt          = (int*)take((size_t)NBUCK * 4);
    int*  bptr          = (int*)take((size_t)(NBUCK + 1) * 4);
    int*  bcursor       = (int*)take((size_t)NBUCK * 4);
    float*  t1          = (float*)take((size_t)N_NODES * DIM * 4);     // aliased: t1/u/t3/u2 (fp32)
    __half* t2h         = (__half*)take((size_t)N_NODES * MROW * 2);   // messages (fp16, 128B rows)
    (void)ws_size; (void)in_sizes; (void)n_in; (void)out_size;

    const int NB64 = (N_NODES + 63) / 64;    // 1563
    const int NB20 = (N_NODES + 19) / 20;    // 5000

    hipMemsetAsync(bcnt, 0, (size_t)NBUCK * 4, stream);
    k_bhist<<<NBLK_E, 256, 0, stream>>>(ei, bcnt);
    k_bscan<<<1, 1024, 0, stream>>>(bcnt, bptr, bcursor);
    k_bin<<<NBLK_E, 256, 0, stream>>>(ei, bcursor, pairs);
    k_sort<<<NBUCK, 256, 0, stream>>>(pairs, bptr, row_ptr, sorted_src);

    k_g1<<<NB64, 256, 0, stream>>>(x, c1_W1, t1, t2h);
    k_aggr<<<NB20, 256, 0, stream>>>(t1, (const uint2*)t2h, row_ptr, sorted_src, c1_b1, t1);
    k_chain1<<<NB64, 256, 0, stream>>>(t1, c1_W2, c1_b2, bn1_g, bn1_b, bn1_m, bn1_v,
                                       c2_W1, t1, t2h);
    k_aggr<<<NB20, 256, 0, stream>>>(t1, (const uint2*)t2h, row_ptr, sorted_src, c2_b1, t1);
    k_chain2<<<NB64, 256, 0, stream>>>(t1, c2_W2, c2_b2, bn2_g, bn2_b, bn2_m, bn2_v,
                                       fc1_W, fc1_b, fc2_W, fc2_b, out);
}

// Round 12
// 272.134 us; speedup vs baseline: 1.3033x; 1.0476x over previous
//
#include <hip/hip_runtime.h>
#include <hip/hip_fp16.h>

#define N_NODES 100000
#define N_EDGES 3200000
#define N_FEAT  128
#define DIM     48
#define N_CLASS 18
#define BN_EPS  1e-5f

#define PADW 136   // f16 MFMA K=128 tile row stride (272 B): 2-way bank alias (free)
#define PADC 72    // f16 MFMA K=64 tile row stride (144 B): 2-way bank alias (free)
#define MROW 64    // padded message-row stride in halfs (128 B = 1 cache line)

#define BSH    7                                   // bucket = dst >> 7 (128 nodes)
#define BROWS  128                                 // nodes per bucket
#define NBUCK  ((N_NODES + BROWS - 1) / BROWS)     // 782
#define BCAP   4608                                // slack bucket window (mean 4092, sigma 64)
#define EPB    4096                                // edges per binning block
#define NBLK_E ((N_EDGES + EPB - 1) / EPB)         // 782

typedef __attribute__((ext_vector_type(8))) _Float16 f16x8;
typedef __attribute__((ext_vector_type(4))) float f32x4;

// packed edge: (src << 7) | (dst & 127).  src < 2^17, fits 24 bits.

// ---------------- binning: direct scatter into slack bucket windows ----------------
// Per block: local bucket histogram -> one global reserve atomic per (block,bucket)
// -> scatter packed edges straight to pairs[bucket_window + base + local_rank].

__global__ __launch_bounds__(256) void k_bin(const int* __restrict__ ei,
                                             int* __restrict__ bcursor,
                                             unsigned int* __restrict__ pairs) {
    __shared__ int h[NBUCK];     // counts, then absolute global write base
    __shared__ int pos[NBUCK];   // local rank cursor
    const int t = threadIdx.x;
    const int bs = blockIdx.x * EPB;
    const int ce = min(EPB, N_EDGES - bs);

    int sv[16], dv[16];
    #pragma unroll
    for (int i = 0; i < 16; i++) {
        int e = t + i * 256;
        if (e < ce) { sv[i] = ei[bs + e]; dv[i] = ei[N_EDGES + bs + e]; }
        else { sv[i] = 0; dv[i] = -1; }
    }
    for (int i = t; i < NBUCK; i += 256) h[i] = 0;
    __syncthreads();
    #pragma unroll
    for (int i = 0; i < 16; i++)
        if (dv[i] >= 0) atomicAdd(&h[dv[i] >> BSH], 1);
    __syncthreads();

    for (int b = t; b < NBUCK; b += 256) {
        int cnt = h[b];
        if (cnt > 0) {
            int g = atomicAdd(&bcursor[b], cnt);
            h[b] = b * BCAP + g;     // absolute base for this block's run in bucket b
        }
        pos[b] = 0;
    }
    __syncthreads();

    #pragma unroll
    for (int i = 0; i < 16; i++) {
        if (dv[i] >= 0) {
            int b = dv[i] >> BSH;
            int p = atomicAdd(&pos[b], 1);
            pairs[h[b] + p] = ((unsigned int)sv[i] << 7) | (unsigned int)(dv[i] & (BROWS - 1));
        }
    }
}

// ---------------- per-bucket counting sort -> slack CSR (row_beg/row_end, sorted_src) ----------------
// Per-wave sub-histograms + per-wave scatter cursors: 4x less LDS-atomic contention.

__global__ __launch_bounds__(256) void k_sort(const unsigned int* __restrict__ pairs,
                                              const int* __restrict__ bcursor,
                                              int* __restrict__ row_beg,
                                              int* __restrict__ row_end,
                                              int* __restrict__ sorted_src) {
    __shared__ int histw[4 * BROWS];   // per-wave hist, later absolute cursors
    __shared__ int woff[4 * BROWS];    // per-wave exclusive offset within node
    __shared__ int tot[BROWS];
    __shared__ int scn[BROWS];
    __shared__ int beg[BROWS];
    const int t = threadIdx.x;
    const int wid = t >> 6;
    const int b = blockIdx.x;
    const int nbase = b << BSH;
    const int start_w = b * BCAP;
    const int cnt = bcursor[b];

    for (int i = t; i < 4 * BROWS; i += 256) histw[i] = 0;
    __syncthreads();
    for (int e = start_w + t; e < start_w + cnt; e += 256)
        atomicAdd(&histw[wid * BROWS + (pairs[e] & (BROWS - 1))], 1);
    __syncthreads();

    if (t < BROWS) {
        int run = 0;
        #pragma unroll
        for (int w = 0; w < 4; w++) {
            woff[w * BROWS + t] = run;
            run += histw[w * BROWS + t];
        }
        tot[t] = run;
        scn[t] = run;
    }
    __syncthreads();
    for (int off = 1; off < BROWS; off <<= 1) {
        int v = 0;
        if (t < BROWS && t >= off) v = scn[t - off];
        __syncthreads();
        if (t < BROWS) scn[t] += v;
        __syncthreads();
    }
    if (t < BROWS) {
        int rb = start_w + scn[t] - tot[t];   // exclusive + window base
        beg[t] = rb;
        int n = nbase + t;
        if (n < N_NODES) {
            row_beg[n] = rb;
            row_end[n] = rb + tot[t];
        }
    }
    __syncthreads();
    if (t < BROWS) {
        #pragma unroll
        for (int w = 0; w < 4; w++)
            histw[w * BROWS + t] = beg[t] + woff[w * BROWS + t];   // absolute cursor
    }
    __syncthreads();
    for (int e = start_w + t; e < start_w + cnt; e += 256) {
        unsigned int p = pairs[e];
        int node = p & (BROWS - 1);
        int idx = atomicAdd(&histw[wid * BROWS + node], 1);
        sorted_src[idx] = (int)(p >> 7);
    }
}

// ---------------- conv1 front (MFMA): t1 = x@W1 (fp32), t2 = relu(x)@W1 (fp16, 128B rows) ----------------

__global__ __launch_bounds__(256) void k_g1(const float* __restrict__ x,
                                            const float* __restrict__ W1,
                                            float* __restrict__ t1,
                                            __half* __restrict__ t2) {
    __shared__ _Float16 sX[64 * PADW];    // 17.4 KB fp16 x-tile [row][k]
    __shared__ _Float16 sW[DIM * PADW];   // 13.1 KB fp16 W^T [col][k]
    const int t = threadIdx.x;
    const int base = blockIdx.x * 64;
    const int wid = t >> 6, lane = t & 63;

    for (int idx = t; idx < DIM * (N_FEAT / 2); idx += 256) {
        int c = idx >> 6;
        int kk = (idx & 63) * 2;
        *(__half2*)&sW[c * PADW + kk] =
            __floats2half2_rn(W1[kk * DIM + c], W1[(kk + 1) * DIM + c]);
    }
    #pragma unroll
    for (int i = 0; i < 8; i++) {
        int idx = t + i * 256;
        int row = idx >> 5, kq = idx & 31;
        float4 v = make_float4(0.f, 0.f, 0.f, 0.f);
        if (base + row < N_NODES) v = ((const float4*)x)[(base + row) * 32 + kq];
        *(__half2*)&sX[row * PADW + kq * 4]     = __floats2half2_rn(v.x, v.y);
        *(__half2*)&sX[row * PADW + kq * 4 + 2] = __floats2half2_rn(v.z, v.w);
    }
    __syncthreads();

    const int r16 = wid * 16;
    const int lrow = lane & 15;
    const int lk = (lane >> 4) * 8;

    f32x4 acc1[3], acc2[3];
    #pragma unroll
    for (int c = 0; c < 3; c++) {
        acc1[c] = (f32x4){0.f, 0.f, 0.f, 0.f};
        acc2[c] = (f32x4){0.f, 0.f, 0.f, 0.f};
    }

    #pragma unroll
    for (int ks = 0; ks < 4; ks++) {
        f16x8 a = *(const f16x8*)&sX[(r16 + lrow) * PADW + ks * 32 + lk];
        f16x8 ra;
        #pragma unroll
        for (int j = 0; j < 8; j++)
            ra[j] = a[j] > (_Float16)0 ? a[j] : (_Float16)0;
        #pragma unroll
        for (int c = 0; c < 3; c++) {
            f16x8 b = *(const f16x8*)&sW[(c * 16 + lrow) * PADW + ks * 32 + lk];
            acc1[c] = __builtin_amdgcn_mfma_f32_16x16x32_f16(a,  b, acc1[c], 0, 0, 0);
            acc2[c] = __builtin_amdgcn_mfma_f32_16x16x32_f16(ra, b, acc2[c], 0, 0, 0);
        }
    }

    const int orow = r16 + (lane >> 4) * 4;
    const int ocol = lane & 15;
    #pragma unroll
    for (int q = 0; q < 4; q++) {
        int gr = base + orow + q;
        if (gr < N_NODES) {
            #pragma unroll
            for (int c = 0; c < 3; c++) {
                t1[gr * DIM + c * 16 + ocol] = acc1[c][q];
                t2[gr * MROW + c * 16 + ocol] = __float2half(acc2[c][q]);
            }
        }
    }
}

// ---------------- aggregation: out = relu(tlin + segsum(tmsg_fp16) + bias) ----------------
// 5 nodes/wave, 12 lanes/node, 8B/lane; message rows padded to 128B (1 line/row).
// out aliases tlin: read-before-write, same thread, row-exclusive.

__device__ inline float2 h2tof2(unsigned int u) {
    __half2 h = *reinterpret_cast<__half2*>(&u);
    return __half22float2(h);
}

__global__ __launch_bounds__(256) void k_aggr(const float* tlin,
                                              const uint2* __restrict__ tmsg8,  // [N][16] 8B chunks
                                              const int* __restrict__ row_beg,
                                              const int* __restrict__ row_end,
                                              const int* __restrict__ ssrc,
                                              const float* __restrict__ bias,
                                              float* out) {
    const int t = threadIdx.x;
    const int wid = t >> 6, lane = t & 63;
    const int sub = lane / 12;
    const int fl  = lane - sub * 12;
    int n = blockIdx.x * 20 + wid * 5 + sub;
    const bool act = (sub < 5) && (n < N_NODES);
    int start = 0, end = 0;
    if (act) { start = row_beg[n]; end = row_end[n]; }

    float ax = 0.f, ay = 0.f, az = 0.f, aw = 0.f;
    int e = start;
    for (; e + 8 <= end; e += 8) {
        int s0 = ssrc[e], s1 = ssrc[e + 1], s2 = ssrc[e + 2], s3 = ssrc[e + 3];
        int s4 = ssrc[e + 4], s5 = ssrc[e + 5], s6 = ssrc[e + 6], s7 = ssrc[e + 7];
        uint2 v0 = tmsg8[s0 * 16 + fl];
        uint2 v1 = tmsg8[s1 * 16 + fl];
        uint2 v2 = tmsg8[s2 * 16 + fl];
        uint2 v3 = tmsg8[s3 * 16 + fl];
        uint2 v4 = tmsg8[s4 * 16 + fl];
        uint2 v5 = tmsg8[s5 * 16 + fl];
        uint2 v6 = tmsg8[s6 * 16 + fl];
        uint2 v7 = tmsg8[s7 * 16 + fl];
        float2 f;
        f = h2tof2(v0.x); ax += f.x; ay += f.y;  f = h2tof2(v0.y); az += f.x; aw += f.y;
        f = h2tof2(v1.x); ax += f.x; ay += f.y;  f = h2tof2(v1.y); az += f.x; aw += f.y;
        f = h2tof2(v2.x); ax += f.x; ay += f.y;  f = h2tof2(v2.y); az += f.x; aw += f.y;
        f = h2tof2(v3.x); ax += f.x; ay += f.y;  f = h2tof2(v3.y); az += f.x; aw += f.y;
        f = h2tof2(v4.x); ax += f.x; ay += f.y;  f = h2tof2(v4.y); az += f.x; aw += f.y;
        f = h2tof2(v5.x); ax += f.x; ay += f.y;  f = h2tof2(v5.y); az += f.x; aw += f.y;
        f = h2tof2(v6.x); ax += f.x; ay += f.y;  f = h2tof2(v6.y); az += f.x; aw += f.y;
        f = h2tof2(v7.x); ax += f.x; ay += f.y;  f = h2tof2(v7.y); az += f.x; aw += f.y;
    }
    for (; e < end; e++) {
        int s = ssrc[e];
        uint2 v = tmsg8[s * 16 + fl];
        float2 f;
        f = h2tof2(v.x); ax += f.x; ay += f.y;
        f = h2tof2(v.y); az += f.x; aw += f.y;
    }
    if (act) {
        float4 base = ((const float4*)tlin)[n * 12 + fl];
        float4 bi   = ((const float4*)bias)[fl];
        float4 r;
        r.x = fmaxf(base.x + ax + bi.x, 0.f);
        r.y = fmaxf(base.y + ay + bi.y, 0.f);
        r.z = fmaxf(base.z + az + bi.z, 0.f);
        r.w = fmaxf(base.w + aw + bi.w, 0.f);
        ((float4*)out)[n * 12 + fl] = r;
    }
}

// ---------------- chain1 (MFMA): v=u@c1W2+b2; g=bn1(relu(v)); t3=g@c2W1 (fp32); t4=relu(g)@c2W1 (fp16, 128B rows) ----------------
// K=48 zero-padded to 64. t3 aliases u (u staged before first sync; writes after; row-exclusive).

__global__ __launch_bounds__(256) void k_chain1(const float* u,
                                                const float* __restrict__ W2,
                                                const float* __restrict__ b2,
                                                const float* __restrict__ bng,
                                                const float* __restrict__ bnb,
                                                const float* __restrict__ bnm,
                                                const float* __restrict__ bnv,
                                                const float* __restrict__ W1n,
                                                float* t3,
                                                __half* __restrict__ t4) {
    __shared__ _Float16 sU[64 * PADC];
    __shared__ _Float16 sG[64 * PADC];
    __shared__ _Float16 sW2t[DIM * PADC];
    __shared__ _Float16 sW1t[DIM * PADC];
    __shared__ float sb2[DIM], ssc[DIM], ssh[DIM];
    const int t = threadIdx.x;
    const int base = blockIdx.x * 64;
    const int wid = t >> 6, lane = t & 63;

    if (t < DIM) {
        sb2[t] = b2[t];
        float sc = bng[t] * rsqrtf(bnv[t] + BN_EPS);
        ssc[t] = sc;
        ssh[t] = bnb[t] - bnm[t] * sc;
    }
    for (int idx = t; idx < DIM * 24; idx += 256) {
        int c = idx / 24, kk = (idx - c * 24) * 2;
        sW2t[c * PADC + kk]     = (_Float16)W2[kk * DIM + c];
        sW2t[c * PADC + kk + 1] = (_Float16)W2[(kk + 1) * DIM + c];
        sW1t[c * PADC + kk]     = (_Float16)W1n[kk * DIM + c];
        sW1t[c * PADC + kk + 1] = (_Float16)W1n[(kk + 1) * DIM + c];
    }
    for (int idx = t; idx < DIM * 16; idx += 256) {
        int c = idx >> 4, j = idx & 15;
        sW2t[c * PADC + 48 + j] = (_Float16)0;
        sW1t[c * PADC + 48 + j] = (_Float16)0;
    }
    for (int idx = t; idx < 64 * 16; idx += 256) {
        int r = idx >> 4, j = idx & 15;
        sU[r * PADC + 48 + j] = (_Float16)0;
        sG[r * PADC + 48 + j] = (_Float16)0;
    }
    for (int idx = t; idx < 64 * 24; idx += 256) {
        int row = idx / 24, kk = (idx - row * 24) * 2;
        float2 v = make_float2(0.f, 0.f);
        if (base + row < N_NODES) v = *(const float2*)&u[(base + row) * DIM + kk];
        sU[row * PADC + kk]     = (_Float16)v.x;
        sU[row * PADC + kk + 1] = (_Float16)v.y;
    }
    __syncthreads();

    const int r16 = wid * 16;
    const int lrow = lane & 15;
    const int lk = (lane >> 4) * 8;
    const int orow = r16 + (lane >> 4) * 4;
    const int ocol = lane & 15;

    f32x4 av[3];
    #pragma unroll
    for (int c = 0; c < 3; c++) av[c] = (f32x4){0.f, 0.f, 0.f, 0.f};
    #pragma unroll
    for (int ks = 0; ks < 2; ks++) {
        f16x8 a = *(const f16x8*)&sU[(r16 + lrow) * PADC + ks * 32 + lk];
        #pragma unroll
        for (int c = 0; c < 3; c++) {
            f16x8 b = *(const f16x8*)&sW2t[(c * 16 + lrow) * PADC + ks * 32 + lk];
            av[c] = __builtin_amdgcn_mfma_f32_16x16x32_f16(a, b, av[c], 0, 0, 0);
        }
    }
    #pragma unroll
    for (int c = 0; c < 3; c++) {
        int col = c * 16 + ocol;
        float bb = sb2[col], sc = ssc[col], sh = ssh[col];
        #pragma unroll
        for (int q = 0; q < 4; q++) {
            float rl = fmaxf(av[c][q] + bb, 0.f);
            sG[(orow + q) * PADC + col] = (_Float16)(rl * sc + sh);
        }
    }
    __syncthreads();

    f32x4 a3[3], a4[3];
    #pragma unroll
    for (int c = 0; c < 3; c++) {
        a3[c] = (f32x4){0.f, 0.f, 0.f, 0.f};
        a4[c] = (f32x4){0.f, 0.f, 0.f, 0.f};
    }
    #pragma unroll
    for (int ks = 0; ks < 2; ks++) {
        f16x8 a = *(const f16x8*)&sG[(r16 + lrow) * PADC + ks * 32 + lk];
        f16x8 ra;
        #pragma unroll
        for (int j = 0; j < 8; j++)
            ra[j] = a[j] > (_Float16)0 ? a[j] : (_Float16)0;
        #pragma unroll
        for (int c = 0; c < 3; c++) {
            f16x8 b = *(const f16x8*)&sW1t[(c * 16 + lrow) * PADC + ks * 32 + lk];
            a3[c] = __builtin_amdgcn_mfma_f32_16x16x32_f16(a,  b, a3[c], 0, 0, 0);
            a4[c] = __builtin_amdgcn_mfma_f32_16x16x32_f16(ra, b, a4[c], 0, 0, 0);
        }
    }
    #pragma unroll
    for (int q = 0; q < 4; q++) {
        int gr = base + orow + q;
        if (gr < N_NODES) {
            #pragma unroll
            for (int c = 0; c < 3; c++) {
                t3[gr * DIM + c * 16 + ocol] = a3[c][q];
                t4[gr * MROW + c * 16 + ocol] = __float2half(a4[c][q]);
            }
        }
    }
}

// ---------------- chain2 (MFMA): v2=u2@c2W2+b2; g2=bn2(relu); z=relu(g2@fc1+b); out=z@fc2+b ----------------

__global__ __launch_bounds__(256) void k_chain2(const float* __restrict__ u2,
                                                const float* __restrict__ W2,
                                                const float* __restrict__ b2,
                                                const float* __restrict__ bng,
                                                const float* __restrict__ bnb,
                                                const float* __restrict__ bnm,
                                                const float* __restrict__ bnv,
                                                const float* __restrict__ fc1W,
                                                const float* __restrict__ fc1b,
                                                const float* __restrict__ fc2W,
                                                const float* __restrict__ fc2b,
                                                float* __restrict__ out) {
    __shared__ _Float16 sA[64 * PADC];
    __shared__ _Float16 sG[64 * PADC];
    __shared__ _Float16 sWa[DIM * PADC];
    __shared__ _Float16 sWb[DIM * PADC];
    __shared__ _Float16 sWc[32 * PADC];
    __shared__ float sb2[DIM], ssc[DIM], ssh[DIM], sfb1[DIM], sfb2[N_CLASS];
    const int t = threadIdx.x;
    const int base = blockIdx.x * 64;
    const int wid = t >> 6, lane = t & 63;

    if (t < DIM) {
        sb2[t] = b2[t];
        float sc = bng[t] * rsqrtf(bnv[t] + BN_EPS);
        ssc[t] = sc;
        ssh[t] = bnb[t] - bnm[t] * sc;
        sfb1[t] = fc1b[t];
    }
    if (t >= 64 && t < 64 + N_CLASS) sfb2[t - 64] = fc2b[t - 64];

    for (int idx = t; idx < DIM * 24; idx += 256) {
        int c = idx / 24, kk = (idx - c * 24) * 2;
        sWa[c * PADC + kk]     = (_Float16)W2[kk * DIM + c];
        sWa[c * PADC + kk + 1] = (_Float16)W2[(kk + 1) * DIM + c];
        sWb[c * PADC + kk]     = (_Float16)fc1W[kk * DIM + c];
        sWb[c * PADC + kk + 1] = (_Float16)fc1W[(kk + 1) * DIM + c];
    }
    for (int idx = t; idx < DIM * 16; idx += 256) {
        int c = idx >> 4, j = idx & 15;
        sWa[c * PADC + 48 + j] = (_Float16)0;
        sWb[c * PADC + 48 + j] = (_Float16)0;
    }
    for (int idx = t; idx < N_CLASS * DIM; idx += 256) {
        int c = idx / DIM, k = idx - c * DIM;
        sWc[c * PADC + k] = (_Float16)fc2W[k * N_CLASS + c];
    }
    for (int idx = t; idx < 32 * 16; idx += 256) {
        int c = idx >> 4, j = idx & 15;
        sWc[c * PADC + 48 + j] = (_Float16)0;
    }
    for (int idx = t; idx < 14 * 48; idx += 256) {
        int c = 18 + idx / 48, k = idx - (idx / 48) * 48;
        sWc[c * PADC + k] = (_Float16)0;
    }
    for (int idx = t; idx < 64 * 16; idx += 256) {
        int r = idx >> 4, j = idx & 15;
        sA[r * PADC + 48 + j] = (_Float16)0;
        sG[r * PADC + 48 + j] = (_Float16)0;
    }
    for (int idx = t; idx < 64 * 24; idx += 256) {
        int row = idx / 24, kk = (idx - row * 24) * 2;
        float2 v = make_float2(0.f, 0.f);
        if (base + row < N_NODES) v = *(const float2*)&u2[(base + row) * DIM + kk];
        sA[row * PADC + kk]     = (_Float16)v.x;
        sA[row * PADC + kk + 1] = (_Float16)v.y;
    }
    __syncthreads();

    const int r16 = wid * 16;
    const int lrow = lane & 15;
    const int lk = (lane >> 4) * 8;
    const int orow = r16 + (lane >> 4) * 4;
    const int ocol = lane & 15;

    {
        f32x4 av[3];
        #pragma unroll
        for (int c = 0; c < 3; c++) av[c] = (f32x4){0.f, 0.f, 0.f, 0.f};
        #pragma unroll
        for (int ks = 0; ks < 2; ks++) {
            f16x8 a = *(const f16x8*)&sA[(r16 + lrow) * PADC + ks * 32 + lk];
            #pragma unroll
            for (int c = 0; c < 3; c++) {
                f16x8 b = *(const f16x8*)&sWa[(c * 16 + lrow) * PADC + ks * 32 + lk];
                av[c] = __builtin_amdgcn_mfma_f32_16x16x32_f16(a, b, av[c], 0, 0, 0);
            }
        }
        #pragma unroll
        for (int c = 0; c < 3; c++) {
            int col = c * 16 + ocol;
            float bb = sb2[col], sc = ssc[col], sh = ssh[col];
            #pragma unroll
            for (int q = 0; q < 4; q++) {
                float rl = fmaxf(av[c][q] + bb, 0.f);
                sG[(orow + q) * PADC + col] = (_Float16)(rl * sc + sh);
            }
        }
    }
    __syncthreads();

    {
        f32x4 az[3];
        #pragma unroll
        for (int c = 0; c < 3; c++) az[c] = (f32x4){0.f, 0.f, 0.f, 0.f};
        #pragma unroll
        for (int ks = 0; ks < 2; ks++) {
            f16x8 a = *(const f16x8*)&sG[(r16 + lrow) * PADC + ks * 32 + lk];
            #pragma unroll
            for (int c = 0; c < 3; c++) {
                f16x8 b = *(const f16x8*)&sWb[(c * 16 + lrow) * PADC + ks * 32 + lk];
                az[c] = __builtin_amdgcn_mfma_f32_16x16x32_f16(a, b, az[c], 0, 0, 0);
            }
        }
        __syncthreads();
        #pragma unroll
        for (int c = 0; c < 3; c++) {
            int col = c * 16 + ocol;
            float bb = sfb1[col];
            #pragma unroll
            for (int q = 0; q < 4; q++)
                sA[(orow + q) * PADC + col] = (_Float16)fmaxf(az[c][q] + bb, 0.f);
        }
    }
    __syncthreads();

    {
        f32x4 ao[2];
        #pragma unroll
        for (int c = 0; c < 2; c++) ao[c] = (f32x4){0.f, 0.f, 0.f, 0.f};
        #pragma unroll
        for (int ks = 0; ks < 2; ks++) {
            f16x8 a = *(const f16x8*)&sA[(r16 + lrow) * PADC + ks * 32 + lk];
            #pragma unroll
            for (int c = 0; c < 2; c++) {
                f16x8 b = *(const f16x8*)&sWc[(c * 16 + lrow) * PADC + ks * 32 + lk];
                ao[c] = __builtin_amdgcn_mfma_f32_16x16x32_f16(a, b, ao[c], 0, 0, 0);
            }
        }
        #pragma unroll
        for (int q = 0; q < 4; q++) {
            int gr = base + orow + q;
            if (gr < N_NODES) {
                #pragma unroll
                for (int c = 0; c < 2; c++) {
                    int col = c * 16 + ocol;
                    if (col < N_CLASS)
                        out[gr * N_CLASS + col] = ao[c][q] + sfb2[col];
                }
            }
        }
    }
}

// ---------------- launch ----------------

extern "C" void kernel_launch(void* const* d_in, const int* in_sizes, int n_in,
                              void* d_out, int out_size, void* d_ws, size_t ws_size,
                              hipStream_t stream) {
    const float* x     = (const float*)d_in[0];
    const int*   ei    = (const int*)d_in[1];
    const float* c1_W1 = (const float*)d_in[2];
    const float* c1_b1 = (const float*)d_in[3];
    const float* c1_W2 = (const float*)d_in[4];
    const float* c1_b2 = (const float*)d_in[5];
    const float* c2_W1 = (const float*)d_in[6];
    const float* c2_b1 = (const float*)d_in[7];
    const float* c2_W2 = (const float*)d_in[8];
    const float* c2_b2 = (const float*)d_in[9];
    const float* bn1_g = (const float*)d_in[10];
    const float* bn1_b = (const float*)d_in[11];
    const float* bn1_m = (const float*)d_in[12];
    const float* bn1_v = (const float*)d_in[13];
    const float* bn2_g = (const float*)d_in[14];
    const float* bn2_b = (const float*)d_in[15];
    const float* bn2_m = (const float*)d_in[16];
    const float* bn2_v = (const float*)d_in[17];
    const float* fc1_W = (const float*)d_in[18];
    const float* fc1_b = (const float*)d_in[19];
    const float* fc2_W = (const float*)d_in[20];
    const float* fc2_b = (const float*)d_in[21];
    float* out = (float*)d_out;

    char* ws = (char*)d_ws;
    size_t o = 0;
    auto take = [&](size_t bytes) {
        void* p = ws + o;
        o = (o + bytes + 255) & ~(size_t)255;
        return p;
    };
    unsigned int* pairs = (unsigned int*)take((size_t)NBUCK * BCAP * 4);   // 14.4 MB (slack windows)
    int*  sorted_src    = (int*)take((size_t)NBUCK * BCAP * 4);            // 14.4 MB (slack windows)
    int*  row_beg       = (int*)take((size_t)N_NODES * 4);
    int*  row_end       = (int*)take((size_t)N_NODES * 4);
    int*  bcursor       = (int*)take((size_t)NBUCK * 4);
    float*  t1          = (float*)take((size_t)N_NODES * DIM * 4);         // aliased: t1/u/t3/u2 (fp32)
    __half* t2h         = (__half*)take((size_t)N_NODES * MROW * 2);       // messages (fp16, 128B rows)
    (void)ws_size; (void)in_sizes; (void)n_in; (void)out_size;

    const int NB64 = (N_NODES + 63) / 64;    // 1563
    const int NB20 = (N_NODES + 19) / 20;    // 5000

    hipMemsetAsync(bcursor, 0, (size_t)NBUCK * 4, stream);
    k_bin<<<NBLK_E, 256, 0, stream>>>(ei, bcursor, pairs);
    k_sort<<<NBUCK, 256, 0, stream>>>(pairs, bcursor, row_beg, row_end, sorted_src);

    k_g1<<<NB64, 256, 0, stream>>>(x, c1_W1, t1, t2h);
    k_aggr<<<NB20, 256, 0, stream>>>(t1, (const uint2*)t2h, row_beg, row_end, sorted_src, c1_b1, t1);
    k_chain1<<<NB64, 256, 0, stream>>>(t1, c1_W2, c1_b2, bn1_g, bn1_b, bn1_m, bn1_v,
                                       c2_W1, t1, t2h);
    k_aggr<<<NB20, 256, 0, stream>>>(t1, (const uint2*)t2h, row_beg, row_end, sorted_src, c2_b1, t1);
    k_chain2<<<NB64, 256, 0, stream>>>(t1, c2_W2, c2_b2, bn2_g, bn2_b, bn2_m, bn2_v,
                                       fc1_W, fc1_b, fc2_W, fc2_b, out);
}